// Round 5
// baseline (665.634 us; speedup 1.0000x reference)
//
#include <hip/hip_runtime.h>
#include <hip/hip_bf16.h>
#include <math.h>

#define N_NODES 100000
#define N_EDGES 1600000
#define TOT_E   (N_EDGES + N_NODES)

__device__ __forceinline__ float lrelu(float v){ return v > 0.f ? v : 0.2f * v; }
__device__ __forceinline__ float elu_(float v){ return v > 0.f ? v : expm1f(v); }
__device__ __forceinline__ ushort f2bf(float f){
  unsigned u = __float_as_uint(f);
  u = (u + 0x7FFFu + ((u >> 16) & 1u)) >> 16;   // RNE
  return (ushort)u;
}

// accumulate 8 bf16 channels (packed in uint4) with weight w
__device__ __forceinline__ void accum8(float w, uint4 hv, float* acc){
  acc[0] = fmaf(w, __uint_as_float(hv.x << 16), acc[0]);
  acc[1] = fmaf(w, __uint_as_float(hv.x & 0xffff0000u), acc[1]);
  acc[2] = fmaf(w, __uint_as_float(hv.y << 16), acc[2]);
  acc[3] = fmaf(w, __uint_as_float(hv.y & 0xffff0000u), acc[3]);
  acc[4] = fmaf(w, __uint_as_float(hv.z << 16), acc[4]);
  acc[5] = fmaf(w, __uint_as_float(hv.z & 0xffff0000u), acc[5]);
  acc[6] = fmaf(w, __uint_as_float(hv.w << 16), acc[6]);
  acc[7] = fmaf(w, __uint_as_float(hv.w & 0xffff0000u), acc[7]);
}
__device__ __forceinline__ void accum4(float w, uint2 zv, float* acc){
  acc[0] = fmaf(w, __uint_as_float(zv.x << 16), acc[0]);
  acc[1] = fmaf(w, __uint_as_float(zv.x & 0xffff0000u), acc[1]);
  acc[2] = fmaf(w, __uint_as_float(zv.y << 16), acc[2]);
  acc[3] = fmaf(w, __uint_as_float(zv.y & 0xffff0000u), acc[3]);
}

// ---------------- CSR build (by dst) ----------------
__global__ __launch_bounds__(256) void k_zero(int* a, int n){
  int i = blockIdx.x * 256 + threadIdx.x;
  if (i < n) a[i] = 0;
}

__global__ __launch_bounds__(256) void k_count(const int* __restrict__ ei, int* __restrict__ cnt){
  int i = blockIdx.x * 256 + threadIdx.x;
  if (i >= TOT_E) return;
  int d = (i < N_EDGES) ? ei[N_EDGES + i] : (i - N_EDGES);
  atomicAdd(&cnt[d], 1);
}

__global__ __launch_bounds__(1024) void k_scan1(const int* __restrict__ cnt, int* __restrict__ off,
                                                int* __restrict__ bs){
  __shared__ int s[1024];
  int t = threadIdx.x;
  int i = blockIdx.x * 1024 + t;
  int v = (i < N_NODES) ? cnt[i] : 0;
  s[t] = v;
  __syncthreads();
  for (int o = 1; o < 1024; o <<= 1){
    int tmp = 0;
    if (t >= o) tmp = s[t - o];
    __syncthreads();
    if (t >= o) s[t] += tmp;
    __syncthreads();
  }
  if (i < N_NODES) off[i] = s[t] - v;
  if (t == 1023) bs[blockIdx.x] = s[1023];
}

__global__ void k_scan2(int* bs, int* off, int nb){
  if (threadIdx.x == 0 && blockIdx.x == 0){
    int base = 0;
    for (int b = 0; b < nb; ++b){ int t = bs[b]; bs[b] = base; base += t; }
    off[N_NODES] = base;
  }
}

__global__ __launch_bounds__(1024) void k_scan3(int* __restrict__ off, int* __restrict__ cur,
                                                const int* __restrict__ bs){
  int i = blockIdx.x * 1024 + threadIdx.x;
  if (i < N_NODES){
    int v = off[i] + bs[blockIdx.x];
    off[i] = v;
    cur[i] = v;
  }
}

__global__ __launch_bounds__(256) void k_fill(const int* __restrict__ ei, int* __restrict__ cur,
                                              int* __restrict__ csr){
  int i = blockIdx.x * 256 + threadIdx.x;
  if (i >= TOT_E) return;
  int s, d;
  if (i < N_EDGES){ s = ei[i]; d = ei[N_EDGES + i]; }
  else            { s = d = i - N_EDGES; }
  int p = atomicAdd(&cur[d], 1);
  csr[p] = s;
}

// ------- layer-1 GEMM fused with alpha1; h stored bf16 (in d_out) -------
__global__ __launch_bounds__(256) void k_gemm1(const float* __restrict__ x, const float* __restrict__ W,
                                               const float* __restrict__ a_src, const float* __restrict__ a_dst,
                                               ushort* __restrict__ h, float* __restrict__ as1,
                                               float* __restrict__ ad1, int n){
  const int cg   = threadIdx.x & 7;     // 8 col-groups of 16
  const int slot = threadIdx.x >> 3;    // 32 slots x 4 rows
  const int r0   = blockIdx.x * 128 + slot * 4;
  const int col0 = cg * 16;

  const float* xp[4];
  #pragma unroll
  for (int i = 0; i < 4; ++i){
    int r = r0 + i; if (r > n - 1) r = n - 1;
    xp[i] = x + (size_t)r * 128;
  }

  float acc[4][16] = {};
  const float* wp = W + col0;
  for (int k = 0; k < 128; ++k){
    float4 w0 = *(const float4*)(wp);
    float4 w1 = *(const float4*)(wp + 4);
    float4 w2 = *(const float4*)(wp + 8);
    float4 w3 = *(const float4*)(wp + 12);
    wp += 128;
    #pragma unroll
    for (int i = 0; i < 4; ++i){
      float xv = xp[i][k];
      acc[i][0]  = fmaf(xv, w0.x, acc[i][0]);  acc[i][1]  = fmaf(xv, w0.y, acc[i][1]);
      acc[i][2]  = fmaf(xv, w0.z, acc[i][2]);  acc[i][3]  = fmaf(xv, w0.w, acc[i][3]);
      acc[i][4]  = fmaf(xv, w1.x, acc[i][4]);  acc[i][5]  = fmaf(xv, w1.y, acc[i][5]);
      acc[i][6]  = fmaf(xv, w1.z, acc[i][6]);  acc[i][7]  = fmaf(xv, w1.w, acc[i][7]);
      acc[i][8]  = fmaf(xv, w2.x, acc[i][8]);  acc[i][9]  = fmaf(xv, w2.y, acc[i][9]);
      acc[i][10] = fmaf(xv, w2.z, acc[i][10]); acc[i][11] = fmaf(xv, w2.w, acc[i][11]);
      acc[i][12] = fmaf(xv, w3.x, acc[i][12]); acc[i][13] = fmaf(xv, w3.y, acc[i][13]);
      acc[i][14] = fmaf(xv, w3.z, acc[i][14]); acc[i][15] = fmaf(xv, w3.w, acc[i][15]);
    }
  }

  #pragma unroll
  for (int i = 0; i < 4; ++i){
    int r = r0 + i;
    float sp = 0.f, dp = 0.f;
    #pragma unroll
    for (int j = 0; j < 16; ++j){
      sp = fmaf(acc[i][j], a_src[col0 + j], sp);
      dp = fmaf(acc[i][j], a_dst[col0 + j], dp);
    }
    float s0 = (col0 < 64) ? sp : 0.f, s1 = (col0 < 64) ? 0.f : sp;
    float d0 = (col0 < 64) ? dp : 0.f, d1 = (col0 < 64) ? 0.f : dp;
    #pragma unroll
    for (int m = 1; m <= 4; m <<= 1){
      s0 += __shfl_xor(s0, m); s1 += __shfl_xor(s1, m);
      d0 += __shfl_xor(d0, m); d1 += __shfl_xor(d1, m);
    }
    if (r < n){
      union { uint4 q[2]; ushort us[16]; } pk;
      #pragma unroll
      for (int j = 0; j < 16; ++j) pk.us[j] = f2bf(acc[i][j]);
      uint4* dst = (uint4*)(h + (size_t)r * 128 + col0);
      dst[0] = pk.q[0]; dst[1] = pk.q[1];
      if (cg == 0){
        as1[2 * r] = s0; as1[2 * r + 1] = s1;
        ad1[2 * r] = d0; ad1[2 * r + 1] = d1;
      }
    }
  }
}

// ------- layer-2 attention vectors: vs[k] = sum_c W2[k,c]*a2[c] -------
__global__ void k_prep2(const float* __restrict__ W2, const float* __restrict__ a_src2,
                        const float* __restrict__ a_dst2, float* __restrict__ vs, float* __restrict__ vd){
  int k = threadIdx.x;  // 128 threads
  float s = 0.f, d = 0.f;
  for (int c = 0; c < 64; ++c){
    float w = W2[k * 64 + c];
    s = fmaf(w, a_src2[c], s);
    d = fmaf(w, a_dst2[c], d);
  }
  vs[k] = s; vd[k] = d;
}

// ------- layer-1 agg: chunk-staged weights in LDS + quarter-wave gather -------
// Phase A: 64 lanes compute 64 edge weights in parallel (1 exp/lane/head).
// Phase B: 4 groups x 16 lanes; each group one edge; lane = ushort8 of h.
// Fused: elu, alpha2, z = y@W2 (bf16).
__global__ __launch_bounds__(256) void k_agg1(const int* __restrict__ off, const int* __restrict__ csr,
                                              const ushort* __restrict__ h, const float* __restrict__ asl,
                                              const float* __restrict__ adl, const float* __restrict__ b,
                                              const float* __restrict__ vs2, const float* __restrict__ vd2,
                                              const float* __restrict__ W2,
                                              ushort* __restrict__ z, float* __restrict__ as2,
                                              float* __restrict__ ad2){
  __shared__ float2 ws1[4][2][64];        // per-wave: {w, src_as_float} per head
  int wid  = threadIdx.x >> 6;
  int node = blockIdx.x * 4 + wid;
  int lane = threadIdx.x & 63;
  int g    = lane >> 4;                   // group 0..3 (edge slot)
  int il   = lane & 15;                   // 8 channels: c0..c0+7
  int c0   = il * 8;
  int hsel = il >> 3;                     // head of my channels
  int s0 = off[node], e0 = off[node + 1];
  float ad0 = adl[2 * node], ad1v = adl[2 * node + 1];

  float acc[8] = {};
  float w0p = 0.f, w1p = 0.f;

  for (int base = s0; base < e0; base += 64){
    int m = e0 - base; if (m > 64) m = 64;
    // phase A: stage 64 weights + srcs
    int k = base + lane;
    float w0 = 0.f, w1 = 0.f; int s = 0;
    if (k < e0){
      s = csr[k];
      float2 a = *(const float2*)(asl + 2u * (unsigned)s);
      w0 = __expf(lrelu(a.x + ad0));
      w1 = __expf(lrelu(a.y + ad1v));
    }
    w0p += w0; w1p += w1;
    ws1[wid][0][lane] = make_float2(w0, __int_as_float(s));
    ws1[wid][1][lane] = make_float2(w1, __int_as_float(s));

    // phase B: quarter-wave gather-accumulate (2 edges in flight per group)
    const float2* wsw = ws1[wid][hsel];
    int i = g;
    for (; i + 4 < m; i += 8){
      float2 A = wsw[i];
      float2 B = wsw[i + 4];
      int sA = __float_as_int(A.y), sB = __float_as_int(B.y);
      uint4 hA = ((const uint4*)(h + ((size_t)sA << 7)))[il];
      uint4 hB = ((const uint4*)(h + ((size_t)sB << 7)))[il];
      accum8(A.x, hA, acc);
      accum8(B.x, hB, acc);
    }
    if (i < m){
      float2 A = wsw[i];
      int sA = __float_as_int(A.y);
      uint4 hA = ((const uint4*)(h + ((size_t)sA << 7)))[il];
      accum8(A.x, hA, acc);
    }
  }

  // reduce over the 4 groups (same il => same channels)
  #pragma unroll
  for (int j = 0; j < 8; ++j){
    acc[j] += __shfl_xor(acc[j], 16);
    acc[j] += __shfl_xor(acc[j], 32);
  }
  // den over all 64 lanes
  #pragma unroll
  for (int mk = 32; mk; mk >>= 1){
    w0p += __shfl_xor(w0p, mk);
    w1p += __shfl_xor(w1p, mk);
  }

  float inv = 1.f / ((hsel ? w1p : w0p) + 1e-16f);
  float o[8];
  #pragma unroll
  for (int j = 0; j < 8; ++j) o[j] = elu_(acc[j] * inv + b[c0 + j]);

  // alpha2 = y . (W2 @ a2): per-lane partial over 8 channels, reduce over il
  float s2 = 0.f, d2 = 0.f;
  #pragma unroll
  for (int j = 0; j < 8; ++j){
    s2 = fmaf(o[j], vs2[c0 + j], s2);
    d2 = fmaf(o[j], vd2[c0 + j], d2);
  }
  #pragma unroll
  for (int mk = 8; mk; mk >>= 1){ s2 += __shfl_xor(s2, mk); d2 += __shfl_xor(d2, mk); }
  if (lane == 0){ as2[node] = s2; ad2[node] = d2; }

  // z[node, lane] = sum_kk y[kk] * W2[kk, lane]; y[q*8+j] lives in lane q (il=q)
  float zacc = 0.f;
  #pragma unroll 2
  for (int q = 0; q < 16; ++q){
    float y0 = __shfl(o[0], q), y1 = __shfl(o[1], q), y2 = __shfl(o[2], q), y3 = __shfl(o[3], q);
    float y4 = __shfl(o[4], q), y5 = __shfl(o[5], q), y6 = __shfl(o[6], q), y7 = __shfl(o[7], q);
    const float* wr = W2 + (q * 8) * 64 + lane;
    zacc = fmaf(y0, wr[0],   zacc);
    zacc = fmaf(y1, wr[64],  zacc);
    zacc = fmaf(y2, wr[128], zacc);
    zacc = fmaf(y3, wr[192], zacc);
    zacc = fmaf(y4, wr[256], zacc);
    zacc = fmaf(y5, wr[320], zacc);
    zacc = fmaf(y6, wr[384], zacc);
    zacc = fmaf(y7, wr[448], zacc);
  }
  z[((size_t)node << 6) + lane] = f2bf(zacc);
}

// ------- layer-2 agg: same two-phase structure over z -------
__global__ __launch_bounds__(256) void k_agg2(const int* __restrict__ off, const int* __restrict__ csr,
                                              const ushort* __restrict__ z, const float* __restrict__ as2,
                                              const float* __restrict__ ad2, const float* __restrict__ b2,
                                              float* __restrict__ out){
  __shared__ float2 ws2[4][64];
  int wid  = threadIdx.x >> 6;
  int node = blockIdx.x * 4 + wid;
  int lane = threadIdx.x & 63;
  int g    = lane >> 4;
  int il   = lane & 15;                   // 4 channels: il*4..il*4+3
  int s0 = off[node], e0 = off[node + 1];
  float adv = ad2[node];

  float acc[4] = {};
  float denp = 0.f;

  for (int base = s0; base < e0; base += 64){
    int m = e0 - base; if (m > 64) m = 64;
    int k = base + lane;
    float w = 0.f; int s = 0;
    if (k < e0){
      s = csr[k];
      w = __expf(lrelu(as2[s] + adv));
    }
    denp += w;
    ws2[wid][lane] = make_float2(w, __int_as_float(s));

    const float2* wsw = ws2[wid];
    int i = g;
    for (; i + 4 < m; i += 8){
      float2 A = wsw[i];
      float2 B = wsw[i + 4];
      int sA = __float_as_int(A.y), sB = __float_as_int(B.y);
      uint2 zA = ((const uint2*)(z + ((size_t)sA << 6)))[il];
      uint2 zB = ((const uint2*)(z + ((size_t)sB << 6)))[il];
      accum4(A.x, zA, acc);
      accum4(B.x, zB, acc);
    }
    if (i < m){
      float2 A = wsw[i];
      int sA = __float_as_int(A.y);
      uint2 zA = ((const uint2*)(z + ((size_t)sA << 6)))[il];
      accum4(A.x, zA, acc);
    }
  }

  #pragma unroll
  for (int j = 0; j < 4; ++j){
    acc[j] += __shfl_xor(acc[j], 16);
    acc[j] += __shfl_xor(acc[j], 32);
  }
  #pragma unroll
  for (int mk = 32; mk; mk >>= 1) denp += __shfl_xor(denp, mk);

  if (lane < 16){
    float inv = 1.f / (denp + 1e-16f);
    float4 o;
    o.x = elu_(acc[0] * inv + b2[lane * 4]);
    o.y = elu_(acc[1] * inv + b2[lane * 4 + 1]);
    o.z = elu_(acc[2] * inv + b2[lane * 4 + 2]);
    o.w = elu_(acc[3] * inv + b2[lane * 4 + 3]);
    *(float4*)(out + ((size_t)node << 6) + lane * 4) = o;
  }
}

// ---------------- host ----------------
extern "C" void kernel_launch(void* const* d_in, const int* in_sizes, int n_in,
                              void* d_out, int out_size, void* d_ws, size_t ws_size,
                              hipStream_t stream){
  const float* x      = (const float*)d_in[0];
  const int*   ei     = (const int*)d_in[1];
  const float* W1     = (const float*)d_in[2];
  const float* a_src1 = (const float*)d_in[3];
  const float* a_dst1 = (const float*)d_in[4];
  const float* b1     = (const float*)d_in[5];
  const float* W2     = (const float*)d_in[6];
  const float* a_src2 = (const float*)d_in[7];
  const float* a_dst2 = (const float*)d_in[8];
  const float* b2     = (const float*)d_in[9];
  float* out = (float*)d_out;

  // workspace (~24 MB); h1 (bf16) lives in d_out until k_agg2 overwrites it
  char* ws = (char*)d_ws;
  size_t o = 0;
  auto alloc = [&](size_t bytes){ size_t r = o; o = (o + bytes + 255) & ~(size_t)255; return r; };
  int*    tmpN = (int*)(ws + alloc((size_t)N_NODES * 4));
  int*    bs   = (int*)(ws + alloc(512));
  int*    off  = (int*)(ws + alloc((size_t)(N_NODES + 1) * 4));
  int*    csr  = (int*)(ws + alloc((size_t)TOT_E * 4));
  float*  as1  = (float*)(ws + alloc((size_t)N_NODES * 2 * 4));
  float*  ad1  = (float*)(ws + alloc((size_t)N_NODES * 2 * 4));
  float*  as2  = (float*)(ws + alloc((size_t)N_NODES * 4));
  float*  ad2  = (float*)(ws + alloc((size_t)N_NODES * 4));
  float*  vs2  = (float*)(ws + alloc(512));
  float*  vd2  = (float*)(ws + alloc(512));
  ushort* z    = (ushort*)(ws + alloc((size_t)N_NODES * 64 * 2));
  ushort* h1   = (ushort*)d_out;
  (void)ws_size; (void)in_sizes; (void)n_in; (void)out_size;

  const int nblk_nodes = (N_NODES + 255) / 256;
  const int nblk_edges = (TOT_E + 255) / 256;
  const int nblk_scan  = (N_NODES + 1023) / 1024;
  const int nblk_wave4 = N_NODES / 4;

  // CSR build
  k_zero <<<nblk_nodes, 256, 0, stream>>>(tmpN, N_NODES);
  k_count<<<nblk_edges, 256, 0, stream>>>(ei, tmpN);
  k_scan1<<<nblk_scan, 1024, 0, stream>>>(tmpN, off, bs);
  k_scan2<<<1, 1, 0, stream>>>(bs, off, nblk_scan);
  k_scan3<<<nblk_scan, 1024, 0, stream>>>(off, tmpN, bs);
  k_fill <<<nblk_edges, 256, 0, stream>>>(ei, tmpN, csr);

  // layer 1 (+ fused alpha1); layer-2 attention vectors
  k_gemm1<<<(N_NODES + 127) / 128, 256, 0, stream>>>(x, W1, a_src1, a_dst1, h1, as1, ad1, N_NODES);
  k_prep2<<<1, 128, 0, stream>>>(W2, a_src2, a_dst2, vs2, vd2);

  // layer-1 agg with fused elu + z = y@W2 + alpha2  (y never materialized)
  k_agg1 <<<nblk_wave4, 256, 0, stream>>>(off, csr, h1, as1, ad1, b1, vs2, vd2, W2, z, as2, ad2);

  // layer-2 agg over z, final elu
  k_agg2 <<<nblk_wave4, 256, 0, stream>>>(off, csr, z, as2, ad2, b2, out);
}

// Round 6
// 652.900 us; speedup vs baseline: 1.0195x; 1.0195x over previous
//
#include <hip/hip_runtime.h>
#include <hip/hip_bf16.h>
#include <math.h>

#define N_NODES 100000
#define N_EDGES 1600000
#define TOT_E   (N_EDGES + N_NODES)

__device__ __forceinline__ float lrelu(float v){ return v > 0.f ? v : 0.2f * v; }
__device__ __forceinline__ float elu_(float v){ return v > 0.f ? v : expm1f(v); }
__device__ __forceinline__ ushort f2bf(float f){
  unsigned u = __float_as_uint(f);
  u = (u + 0x7FFFu + ((u >> 16) & 1u)) >> 16;   // RNE
  return (ushort)u;
}

// accumulate 8 bf16 channels (packed uint4) with weight w
__device__ __forceinline__ void accum8(float w, uint4 hv, float* acc){
  acc[0] = fmaf(w, __uint_as_float(hv.x << 16), acc[0]);
  acc[1] = fmaf(w, __uint_as_float(hv.x & 0xffff0000u), acc[1]);
  acc[2] = fmaf(w, __uint_as_float(hv.y << 16), acc[2]);
  acc[3] = fmaf(w, __uint_as_float(hv.y & 0xffff0000u), acc[3]);
  acc[4] = fmaf(w, __uint_as_float(hv.z << 16), acc[4]);
  acc[5] = fmaf(w, __uint_as_float(hv.z & 0xffff0000u), acc[5]);
  acc[6] = fmaf(w, __uint_as_float(hv.w << 16), acc[6]);
  acc[7] = fmaf(w, __uint_as_float(hv.w & 0xffff0000u), acc[7]);
}
__device__ __forceinline__ void accum4(float w, uint2 zv, float* acc){
  acc[0] = fmaf(w, __uint_as_float(zv.x << 16), acc[0]);
  acc[1] = fmaf(w, __uint_as_float(zv.x & 0xffff0000u), acc[1]);
  acc[2] = fmaf(w, __uint_as_float(zv.y << 16), acc[2]);
  acc[3] = fmaf(w, __uint_as_float(zv.y & 0xffff0000u), acc[3]);
}

// ---------------- CSR build (by dst) ----------------
__global__ __launch_bounds__(256) void k_zero(int* a, int n){
  int i = blockIdx.x * 256 + threadIdx.x;
  if (i < n) a[i] = 0;
}

__global__ __launch_bounds__(256) void k_count(const int* __restrict__ ei, int* __restrict__ cnt){
  int i = blockIdx.x * 256 + threadIdx.x;
  if (i >= TOT_E) return;
  int d = (i < N_EDGES) ? ei[N_EDGES + i] : (i - N_EDGES);
  atomicAdd(&cnt[d], 1);
}

__global__ __launch_bounds__(1024) void k_scan1(const int* __restrict__ cnt, int* __restrict__ off,
                                                int* __restrict__ bs){
  __shared__ int s[1024];
  int t = threadIdx.x;
  int i = blockIdx.x * 1024 + t;
  int v = (i < N_NODES) ? cnt[i] : 0;
  s[t] = v;
  __syncthreads();
  for (int o = 1; o < 1024; o <<= 1){
    int tmp = 0;
    if (t >= o) tmp = s[t - o];
    __syncthreads();
    if (t >= o) s[t] += tmp;
    __syncthreads();
  }
  if (i < N_NODES) off[i] = s[t] - v;
  if (t == 1023) bs[blockIdx.x] = s[1023];
}

__global__ void k_scan2(int* bs, int* off, int nb){
  if (threadIdx.x == 0 && blockIdx.x == 0){
    int base = 0;
    for (int b = 0; b < nb; ++b){ int t = bs[b]; bs[b] = base; base += t; }
    off[N_NODES] = base;
  }
}

__global__ __launch_bounds__(1024) void k_scan3(int* __restrict__ off, int* __restrict__ cur,
                                                const int* __restrict__ bs){
  int i = blockIdx.x * 1024 + threadIdx.x;
  if (i < N_NODES){
    int v = off[i] + bs[blockIdx.x];
    off[i] = v;
    cur[i] = v;
  }
}

__global__ __launch_bounds__(256) void k_fill(const int* __restrict__ ei, int* __restrict__ cur,
                                              int* __restrict__ csr){
  int i = blockIdx.x * 256 + threadIdx.x;
  if (i >= TOT_E) return;
  int s, d;
  if (i < N_EDGES){ s = ei[i]; d = ei[N_EDGES + i]; }
  else            { s = d = i - N_EDGES; }
  int p = atomicAdd(&cur[d], 1);
  csr[p] = s;
}

// ------- layer-1 GEMM fused with alpha1; h stored bf16 (in d_out) -------
__global__ __launch_bounds__(256) void k_gemm1(const float* __restrict__ x, const float* __restrict__ W,
                                               const float* __restrict__ a_src, const float* __restrict__ a_dst,
                                               ushort* __restrict__ h, float* __restrict__ as1,
                                               float* __restrict__ ad1, int n){
  const int cg   = threadIdx.x & 7;     // 8 col-groups of 16
  const int slot = threadIdx.x >> 3;    // 32 slots x 4 rows
  const int r0   = blockIdx.x * 128 + slot * 4;
  const int col0 = cg * 16;

  const float* xp[4];
  #pragma unroll
  for (int i = 0; i < 4; ++i){
    int r = r0 + i; if (r > n - 1) r = n - 1;
    xp[i] = x + (size_t)r * 128;
  }

  float acc[4][16] = {};
  const float* wp = W + col0;
  for (int k = 0; k < 128; ++k){
    float4 w0 = *(const float4*)(wp);
    float4 w1 = *(const float4*)(wp + 4);
    float4 w2 = *(const float4*)(wp + 8);
    float4 w3 = *(const float4*)(wp + 12);
    wp += 128;
    #pragma unroll
    for (int i = 0; i < 4; ++i){
      float xv = xp[i][k];
      acc[i][0]  = fmaf(xv, w0.x, acc[i][0]);  acc[i][1]  = fmaf(xv, w0.y, acc[i][1]);
      acc[i][2]  = fmaf(xv, w0.z, acc[i][2]);  acc[i][3]  = fmaf(xv, w0.w, acc[i][3]);
      acc[i][4]  = fmaf(xv, w1.x, acc[i][4]);  acc[i][5]  = fmaf(xv, w1.y, acc[i][5]);
      acc[i][6]  = fmaf(xv, w1.z, acc[i][6]);  acc[i][7]  = fmaf(xv, w1.w, acc[i][7]);
      acc[i][8]  = fmaf(xv, w2.x, acc[i][8]);  acc[i][9]  = fmaf(xv, w2.y, acc[i][9]);
      acc[i][10] = fmaf(xv, w2.z, acc[i][10]); acc[i][11] = fmaf(xv, w2.w, acc[i][11]);
      acc[i][12] = fmaf(xv, w3.x, acc[i][12]); acc[i][13] = fmaf(xv, w3.y, acc[i][13]);
      acc[i][14] = fmaf(xv, w3.z, acc[i][14]); acc[i][15] = fmaf(xv, w3.w, acc[i][15]);
    }
  }

  #pragma unroll
  for (int i = 0; i < 4; ++i){
    int r = r0 + i;
    float sp = 0.f, dp = 0.f;
    #pragma unroll
    for (int j = 0; j < 16; ++j){
      sp = fmaf(acc[i][j], a_src[col0 + j], sp);
      dp = fmaf(acc[i][j], a_dst[col0 + j], dp);
    }
    float s0 = (col0 < 64) ? sp : 0.f, s1 = (col0 < 64) ? 0.f : sp;
    float d0 = (col0 < 64) ? dp : 0.f, d1 = (col0 < 64) ? 0.f : dp;
    #pragma unroll
    for (int m = 1; m <= 4; m <<= 1){
      s0 += __shfl_xor(s0, m); s1 += __shfl_xor(s1, m);
      d0 += __shfl_xor(d0, m); d1 += __shfl_xor(d1, m);
    }
    if (r < n){
      union { uint4 q[2]; ushort us[16]; } pk;
      #pragma unroll
      for (int j = 0; j < 16; ++j) pk.us[j] = f2bf(acc[i][j]);
      uint4* dst = (uint4*)(h + (size_t)r * 128 + col0);
      dst[0] = pk.q[0]; dst[1] = pk.q[1];
      if (cg == 0){
        as1[2 * r] = s0; as1[2 * r + 1] = s1;
        ad1[2 * r] = d0; ad1[2 * r + 1] = d1;
      }
    }
  }
}

// ------- layer-2 attention vectors: vs[k] = sum_c W2[k,c]*a2[c] -------
__global__ void k_prep2(const float* __restrict__ W2, const float* __restrict__ a_src2,
                        const float* __restrict__ a_dst2, float* __restrict__ vs, float* __restrict__ vd){
  int k = threadIdx.x;  // 128 threads
  float s = 0.f, d = 0.f;
  for (int c = 0; c < 64; ++c){
    float w = W2[k * 64 + c];
    s = fmaf(w, a_src2[c], s);
    d = fmaf(w, a_dst2[c], d);
  }
  vs[k] = s; vd[k] = d;
}

// ------- layer-1 agg: quarter-wave (4 edges in flight, x2 unroll = 8 streams) -------
__global__ __launch_bounds__(256) void k_agg1(const int* __restrict__ off, const int* __restrict__ csr,
                                              const ushort* __restrict__ h, const float* __restrict__ asl,
                                              const float* __restrict__ adl, const float* __restrict__ b,
                                              const float* __restrict__ vs2, const float* __restrict__ vd2,
                                              const float* __restrict__ W2,
                                              ushort* __restrict__ z, float* __restrict__ as2,
                                              float* __restrict__ ad2){
  int node = blockIdx.x * 4 + (threadIdx.x >> 6);
  int lane = threadIdx.x & 63;
  int g    = lane >> 4;                   // quarter (edge slot)
  int il   = lane & 15;                   // channel group: c0..c0+7
  int c0   = il * 8;
  int hsel = il >> 3;                     // head of my channels
  int s0 = off[node], e0 = off[node + 1];
  float2 advv = *(const float2*)(adl + 2u * (unsigned)node);
  float adv = hsel ? advv.y : advv.x;

  float acc[8] = {};
  float denp = 0.f;

  int k = s0 + g;
  for (; k + 4 < e0; k += 8){            // 2 edges per quarter per iter
    int sA = csr[k], sB = csr[k + 4];
    float lA = asl[2u * (unsigned)sA + hsel];
    float lB = asl[2u * (unsigned)sB + hsel];
    uint4 hA = ((const uint4*)(h + ((size_t)sA << 7)))[il];
    uint4 hB = ((const uint4*)(h + ((size_t)sB << 7)))[il];
    float wA = __expf(lrelu(lA + adv));
    float wB = __expf(lrelu(lB + adv));
    denp += wA + wB;
    accum8(wA, hA, acc);
    accum8(wB, hB, acc);
  }
  if (k < e0){
    int sA = csr[k];
    float lA = asl[2u * (unsigned)sA + hsel];
    uint4 hA = ((const uint4*)(h + ((size_t)sA << 7)))[il];
    float wA = __expf(lrelu(lA + adv));
    denp += wA;
    accum8(wA, hA, acc);
  }

  // reduce over the 4 quarters (same il => same channels, same head)
  #pragma unroll
  for (int j = 0; j < 8; ++j){
    acc[j] += __shfl_xor(acc[j], 16);
    acc[j] += __shfl_xor(acc[j], 32);
  }
  denp += __shfl_xor(denp, 16);
  denp += __shfl_xor(denp, 32);

  float inv = 1.f / (denp + 1e-16f);
  float o[8];
  #pragma unroll
  for (int j = 0; j < 8; ++j) o[j] = elu_(acc[j] * inv + b[c0 + j]);

  // alpha2 = y . (W2 @ a2): per-lane partial over 8 channels, reduce over il
  float s2 = 0.f, d2 = 0.f;
  #pragma unroll
  for (int j = 0; j < 8; ++j){
    s2 = fmaf(o[j], vs2[c0 + j], s2);
    d2 = fmaf(o[j], vd2[c0 + j], d2);
  }
  #pragma unroll
  for (int mk = 8; mk; mk >>= 1){ s2 += __shfl_xor(s2, mk); d2 += __shfl_xor(d2, mk); }
  if (lane == 0){ as2[node] = s2; ad2[node] = d2; }

  // z[node, c] = sum_kk y[kk] * W2[kk, c]; y[q*8+j] lives in lane q (il=q, quarter 0)
  float zacc = 0.f;
  #pragma unroll 2
  for (int q = 0; q < 16; ++q){
    float y0 = __shfl(o[0], q), y1 = __shfl(o[1], q), y2 = __shfl(o[2], q), y3 = __shfl(o[3], q);
    float y4 = __shfl(o[4], q), y5 = __shfl(o[5], q), y6 = __shfl(o[6], q), y7 = __shfl(o[7], q);
    const float* wr = W2 + (q * 8) * 64 + lane;
    zacc = fmaf(y0, wr[0],   zacc);
    zacc = fmaf(y1, wr[64],  zacc);
    zacc = fmaf(y2, wr[128], zacc);
    zacc = fmaf(y3, wr[192], zacc);
    zacc = fmaf(y4, wr[256], zacc);
    zacc = fmaf(y5, wr[320], zacc);
    zacc = fmaf(y6, wr[384], zacc);
    zacc = fmaf(y7, wr[448], zacc);
  }
  z[((size_t)node << 6) + lane] = f2bf(zacc);
}

// ------- layer-2 agg: quarter-wave over z rows (128B/edge) -------
__global__ __launch_bounds__(256) void k_agg2(const int* __restrict__ off, const int* __restrict__ csr,
                                              const ushort* __restrict__ z, const float* __restrict__ as2,
                                              const float* __restrict__ ad2, const float* __restrict__ b2,
                                              float* __restrict__ out){
  int node = blockIdx.x * 4 + (threadIdx.x >> 6);
  int lane = threadIdx.x & 63;
  int g    = lane >> 4;
  int il   = lane & 15;                   // 4 channels: il*4..il*4+3
  int s0 = off[node], e0 = off[node + 1];
  float adv = ad2[node];

  float acc[4] = {};
  float denp = 0.f;

  int k = s0 + g;
  for (; k + 4 < e0; k += 8){
    int sA = csr[k], sB = csr[k + 4];
    float lA = as2[sA];
    float lB = as2[sB];
    uint2 zA = ((const uint2*)(z + ((size_t)sA << 6)))[il];
    uint2 zB = ((const uint2*)(z + ((size_t)sB << 6)))[il];
    float wA = __expf(lrelu(lA + adv));
    float wB = __expf(lrelu(lB + adv));
    denp += wA + wB;
    accum4(wA, zA, acc);
    accum4(wB, zB, acc);
  }
  if (k < e0){
    int sA = csr[k];
    float lA = as2[sA];
    uint2 zA = ((const uint2*)(z + ((size_t)sA << 6)))[il];
    float wA = __expf(lrelu(lA + adv));
    denp += wA;
    accum4(wA, zA, acc);
  }

  #pragma unroll
  for (int j = 0; j < 4; ++j){
    acc[j] += __shfl_xor(acc[j], 16);
    acc[j] += __shfl_xor(acc[j], 32);
  }
  denp += __shfl_xor(denp, 16);
  denp += __shfl_xor(denp, 32);

  if (lane < 16){
    float inv = 1.f / (denp + 1e-16f);
    float4 o;
    o.x = elu_(acc[0] * inv + b2[lane * 4]);
    o.y = elu_(acc[1] * inv + b2[lane * 4 + 1]);
    o.z = elu_(acc[2] * inv + b2[lane * 4 + 2]);
    o.w = elu_(acc[3] * inv + b2[lane * 4 + 3]);
    *(float4*)(out + ((size_t)node << 6) + lane * 4) = o;
  }
}

// ---------------- host ----------------
extern "C" void kernel_launch(void* const* d_in, const int* in_sizes, int n_in,
                              void* d_out, int out_size, void* d_ws, size_t ws_size,
                              hipStream_t stream){
  const float* x      = (const float*)d_in[0];
  const int*   ei     = (const int*)d_in[1];
  const float* W1     = (const float*)d_in[2];
  const float* a_src1 = (const float*)d_in[3];
  const float* a_dst1 = (const float*)d_in[4];
  const float* b1     = (const float*)d_in[5];
  const float* W2     = (const float*)d_in[6];
  const float* a_src2 = (const float*)d_in[7];
  const float* a_dst2 = (const float*)d_in[8];
  const float* b2     = (const float*)d_in[9];
  float* out = (float*)d_out;

  // workspace (~24 MB); h1 (bf16) lives in d_out until k_agg2 overwrites it
  char* ws = (char*)d_ws;
  size_t o = 0;
  auto alloc = [&](size_t bytes){ size_t r = o; o = (o + bytes + 255) & ~(size_t)255; return r; };
  int*    tmpN = (int*)(ws + alloc((size_t)N_NODES * 4));
  int*    bs   = (int*)(ws + alloc(512));
  int*    off  = (int*)(ws + alloc((size_t)(N_NODES + 1) * 4));
  int*    csr  = (int*)(ws + alloc((size_t)TOT_E * 4));
  float*  as1  = (float*)(ws + alloc((size_t)N_NODES * 2 * 4));
  float*  ad1  = (float*)(ws + alloc((size_t)N_NODES * 2 * 4));
  float*  as2  = (float*)(ws + alloc((size_t)N_NODES * 4));
  float*  ad2  = (float*)(ws + alloc((size_t)N_NODES * 4));
  float*  vs2  = (float*)(ws + alloc(512));
  float*  vd2  = (float*)(ws + alloc(512));
  ushort* z    = (ushort*)(ws + alloc((size_t)N_NODES * 64 * 2));
  ushort* h1   = (ushort*)d_out;
  (void)ws_size; (void)in_sizes; (void)n_in; (void)out_size;

  const int nblk_nodes = (N_NODES + 255) / 256;
  const int nblk_edges = (TOT_E + 255) / 256;
  const int nblk_scan  = (N_NODES + 1023) / 1024;
  const int nblk_wave4 = N_NODES / 4;

  // CSR build
  k_zero <<<nblk_nodes, 256, 0, stream>>>(tmpN, N_NODES);
  k_count<<<nblk_edges, 256, 0, stream>>>(ei, tmpN);
  k_scan1<<<nblk_scan, 1024, 0, stream>>>(tmpN, off, bs);
  k_scan2<<<1, 1, 0, stream>>>(bs, off, nblk_scan);
  k_scan3<<<nblk_scan, 1024, 0, stream>>>(off, tmpN, bs);
  k_fill <<<nblk_edges, 256, 0, stream>>>(ei, tmpN, csr);

  // layer 1 (+ fused alpha1); layer-2 attention vectors
  k_gemm1<<<(N_NODES + 127) / 128, 256, 0, stream>>>(x, W1, a_src1, a_dst1, h1, as1, ad1, N_NODES);
  k_prep2<<<1, 128, 0, stream>>>(W2, a_src2, a_dst2, vs2, vd2);

  // layer-1 agg with fused elu + z = y@W2 + alpha2  (y never materialized)
  k_agg1 <<<nblk_wave4, 256, 0, stream>>>(off, csr, h1, as1, ad1, b1, vs2, vd2, W2, z, as2, ad2);

  // layer-2 agg over z, final elu
  k_agg2 <<<nblk_wave4, 256, 0, stream>>>(off, csr, z, as2, ad2, b2, out);
}

// Round 7
// 586.796 us; speedup vs baseline: 1.1344x; 1.1127x over previous
//
#include <hip/hip_runtime.h>
#include <hip/hip_bf16.h>
#include <math.h>

#define N_NODES 100000
#define N_EDGES 1600000
#define TOT_E   (N_EDGES + N_NODES)

__device__ __forceinline__ float lrelu(float v){ return v > 0.f ? v : 0.2f * v; }
__device__ __forceinline__ float elu_(float v){ return v > 0.f ? v : expm1f(v); }
__device__ __forceinline__ ushort f2bf(float f){
  unsigned u = __float_as_uint(f);
  u = (u + 0x7FFFu + ((u >> 16) & 1u)) >> 16;   // RNE
  return (ushort)u;
}
__device__ __forceinline__ float bf2f(ushort u){
  return __uint_as_float(((unsigned)u) << 16);
}

// ---------------- CSR build (by dst) ----------------
__global__ __launch_bounds__(256) void k_zero(int* a, int n){
  int i = blockIdx.x * 256 + threadIdx.x;
  if (i < n) a[i] = 0;
}

__global__ __launch_bounds__(256) void k_count(const int* __restrict__ ei, int* __restrict__ cnt){
  int i = blockIdx.x * 256 + threadIdx.x;
  if (i >= TOT_E) return;
  int d = (i < N_EDGES) ? ei[N_EDGES + i] : (i - N_EDGES);
  atomicAdd(&cnt[d], 1);
}

__global__ __launch_bounds__(1024) void k_scan1(const int* __restrict__ cnt, int* __restrict__ off,
                                                int* __restrict__ bs){
  __shared__ int s[1024];
  int t = threadIdx.x;
  int i = blockIdx.x * 1024 + t;
  int v = (i < N_NODES) ? cnt[i] : 0;
  s[t] = v;
  __syncthreads();
  for (int o = 1; o < 1024; o <<= 1){
    int tmp = 0;
    if (t >= o) tmp = s[t - o];
    __syncthreads();
    if (t >= o) s[t] += tmp;
    __syncthreads();
  }
  if (i < N_NODES) off[i] = s[t] - v;
  if (t == 1023) bs[blockIdx.x] = s[1023];
}

__global__ void k_scan2(int* bs, int* off, int nb){
  if (threadIdx.x == 0 && blockIdx.x == 0){
    int base = 0;
    for (int b = 0; b < nb; ++b){ int t = bs[b]; bs[b] = base; base += t; }
    off[N_NODES] = base;
  }
}

__global__ __launch_bounds__(1024) void k_scan3(int* __restrict__ off, int* __restrict__ cur,
                                                const int* __restrict__ bs){
  int i = blockIdx.x * 1024 + threadIdx.x;
  if (i < N_NODES){
    int v = off[i] + bs[blockIdx.x];
    off[i] = v;
    cur[i] = v;
  }
}

// fill CSR + dst-per-slot + layer-1 edge weights (runs AFTER gemm1)
__global__ __launch_bounds__(256) void k_fill_w(const int* __restrict__ ei, int* __restrict__ cur,
                                                int* __restrict__ csr, int* __restrict__ edst,
                                                const float* __restrict__ as1, const float* __restrict__ ad1,
                                                float2* __restrict__ w1){
  int i = blockIdx.x * 256 + threadIdx.x;
  if (i >= TOT_E) return;
  int s, d;
  if (i < N_EDGES){ s = ei[i]; d = ei[N_EDGES + i]; }
  else            { s = d = i - N_EDGES; }
  int p = atomicAdd(&cur[d], 1);
  csr[p] = s;
  edst[p] = d;
  float2 a  = *(const float2*)(as1 + 2u * (unsigned)s);
  float2 ad = *(const float2*)(ad1 + 2u * (unsigned)d);
  float2 w;
  w.x = __expf(lrelu(a.x + ad.x));
  w.y = __expf(lrelu(a.y + ad.y));
  w1[p] = w;
}

// layer-2 edge weights (runs AFTER agg1): slot-ordered stream
__global__ __launch_bounds__(256) void k_ew2(const int* __restrict__ csr, const int* __restrict__ edst,
                                             const float* __restrict__ as2, const float* __restrict__ ad2,
                                             float* __restrict__ w2){
  int i = blockIdx.x * 256 + threadIdx.x;
  if (i >= TOT_E) return;
  w2[i] = __expf(lrelu(as2[csr[i]] + ad2[edst[i]]));
}

// ------- layer-1 GEMM fused with alpha1; h stored bf16 (in d_out) -------
__global__ __launch_bounds__(256) void k_gemm1(const float* __restrict__ x, const float* __restrict__ W,
                                               const float* __restrict__ a_src, const float* __restrict__ a_dst,
                                               ushort* __restrict__ h, float* __restrict__ as1,
                                               float* __restrict__ ad1, int n){
  const int cg   = threadIdx.x & 7;     // 8 col-groups of 16
  const int slot = threadIdx.x >> 3;    // 32 slots x 4 rows
  const int r0   = blockIdx.x * 128 + slot * 4;
  const int col0 = cg * 16;

  const float* xp[4];
  #pragma unroll
  for (int i = 0; i < 4; ++i){
    int r = r0 + i; if (r > n - 1) r = n - 1;
    xp[i] = x + (size_t)r * 128;
  }

  float acc[4][16] = {};
  const float* wp = W + col0;
  for (int k = 0; k < 128; ++k){
    float4 w0 = *(const float4*)(wp);
    float4 w1 = *(const float4*)(wp + 4);
    float4 w2 = *(const float4*)(wp + 8);
    float4 w3 = *(const float4*)(wp + 12);
    wp += 128;
    #pragma unroll
    for (int i = 0; i < 4; ++i){
      float xv = xp[i][k];
      acc[i][0]  = fmaf(xv, w0.x, acc[i][0]);  acc[i][1]  = fmaf(xv, w0.y, acc[i][1]);
      acc[i][2]  = fmaf(xv, w0.z, acc[i][2]);  acc[i][3]  = fmaf(xv, w0.w, acc[i][3]);
      acc[i][4]  = fmaf(xv, w1.x, acc[i][4]);  acc[i][5]  = fmaf(xv, w1.y, acc[i][5]);
      acc[i][6]  = fmaf(xv, w1.z, acc[i][6]);  acc[i][7]  = fmaf(xv, w1.w, acc[i][7]);
      acc[i][8]  = fmaf(xv, w2.x, acc[i][8]);  acc[i][9]  = fmaf(xv, w2.y, acc[i][9]);
      acc[i][10] = fmaf(xv, w2.z, acc[i][10]); acc[i][11] = fmaf(xv, w2.w, acc[i][11]);
      acc[i][12] = fmaf(xv, w3.x, acc[i][12]); acc[i][13] = fmaf(xv, w3.y, acc[i][13]);
      acc[i][14] = fmaf(xv, w3.z, acc[i][14]); acc[i][15] = fmaf(xv, w3.w, acc[i][15]);
    }
  }

  #pragma unroll
  for (int i = 0; i < 4; ++i){
    int r = r0 + i;
    float sp = 0.f, dp = 0.f;
    #pragma unroll
    for (int j = 0; j < 16; ++j){
      sp = fmaf(acc[i][j], a_src[col0 + j], sp);
      dp = fmaf(acc[i][j], a_dst[col0 + j], dp);
    }
    float s0 = (col0 < 64) ? sp : 0.f, s1 = (col0 < 64) ? 0.f : sp;
    float d0 = (col0 < 64) ? dp : 0.f, d1 = (col0 < 64) ? 0.f : dp;
    #pragma unroll
    for (int m = 1; m <= 4; m <<= 1){
      s0 += __shfl_xor(s0, m); s1 += __shfl_xor(s1, m);
      d0 += __shfl_xor(d0, m); d1 += __shfl_xor(d1, m);
    }
    if (r < n){
      union { uint4 q[2]; ushort us[16]; } pk;
      #pragma unroll
      for (int j = 0; j < 16; ++j) pk.us[j] = f2bf(acc[i][j]);
      uint4* dst = (uint4*)(h + (size_t)r * 128 + col0);
      dst[0] = pk.q[0]; dst[1] = pk.q[1];
      if (cg == 0){
        as1[2 * r] = s0; as1[2 * r + 1] = s1;
        ad1[2 * r] = d0; ad1[2 * r + 1] = d1;
      }
    }
  }
}

// ------- layer-2 attention vectors: vs[k] = sum_c W2[k,c]*a2[c] -------
__global__ void k_prep2(const float* __restrict__ W2, const float* __restrict__ a_src2,
                        const float* __restrict__ a_dst2, float* __restrict__ vs, float* __restrict__ vd){
  int k = threadIdx.x;  // 128 threads
  float s = 0.f, d = 0.f;
  for (int c = 0; c < 64; ++c){
    float w = W2[k * 64 + c];
    s = fmaf(w, a_src2[c], s);
    d = fmaf(w, a_dst2[c], d);
  }
  vs[k] = s; vd[k] = d;
}

// ------- layer-1 agg: half-wave (R4 pattern), streaming weights, no exp -------
// lanes 0-31 even CSR slots, 32-63 odd; lane covers channels 4*hl..4*hl+3.
// Fused: elu, alpha2, z = y@W2 (bf16).
__global__ __launch_bounds__(256) void k_agg1(const int* __restrict__ off, const int* __restrict__ csr,
                                              const ushort* __restrict__ h, const float* __restrict__ w1,
                                              const float* __restrict__ b,
                                              const float* __restrict__ vs2, const float* __restrict__ vd2,
                                              const float* __restrict__ W2,
                                              ushort* __restrict__ z, float* __restrict__ as2,
                                              float* __restrict__ ad2){
  int node = blockIdx.x * 4 + (threadIdx.x >> 6);
  int lane = threadIdx.x & 63;
  int hl   = lane & 31;
  int half = lane >> 5;
  int head = hl >> 4;
  int c0   = hl * 4;
  int s0 = off[node], e0 = off[node + 1];

  float acc0 = 0.f, acc1 = 0.f, acc2 = 0.f, acc3 = 0.f, denp = 0.f;
  int k = s0 + half;
  for (; k + 2 < e0; k += 4){
    int sA = csr[k], sB = csr[k + 2];
    float wA = w1[2u * (unsigned)k + head];
    float wB = w1[2u * (unsigned)(k + 2) + head];
    ushort4 hA = *(const ushort4*)(h + ((unsigned)sA << 7) + c0);
    ushort4 hB = *(const ushort4*)(h + ((unsigned)sB << 7) + c0);
    denp += wA + wB;
    acc0 = fmaf(wA, bf2f(hA.x), acc0); acc1 = fmaf(wA, bf2f(hA.y), acc1);
    acc2 = fmaf(wA, bf2f(hA.z), acc2); acc3 = fmaf(wA, bf2f(hA.w), acc3);
    acc0 = fmaf(wB, bf2f(hB.x), acc0); acc1 = fmaf(wB, bf2f(hB.y), acc1);
    acc2 = fmaf(wB, bf2f(hB.z), acc2); acc3 = fmaf(wB, bf2f(hB.w), acc3);
  }
  if (k < e0){
    int sA = csr[k];
    float wA = w1[2u * (unsigned)k + head];
    ushort4 hA = *(const ushort4*)(h + ((unsigned)sA << 7) + c0);
    denp += wA;
    acc0 = fmaf(wA, bf2f(hA.x), acc0); acc1 = fmaf(wA, bf2f(hA.y), acc1);
    acc2 = fmaf(wA, bf2f(hA.z), acc2); acc3 = fmaf(wA, bf2f(hA.w), acc3);
  }

  // combine even/odd halves (lane <-> lane^32, same channels, same head)
  acc0 += __shfl_xor(acc0, 32); acc1 += __shfl_xor(acc1, 32);
  acc2 += __shfl_xor(acc2, 32); acc3 += __shfl_xor(acc3, 32);
  denp += __shfl_xor(denp, 32);

  float inv = 1.f / (denp + 1e-16f);
  float o0 = elu_(acc0 * inv + b[c0]);
  float o1 = elu_(acc1 * inv + b[c0 + 1]);
  float o2 = elu_(acc2 * inv + b[c0 + 2]);
  float o3 = elu_(acc3 * inv + b[c0 + 3]);

  // alpha2 = y . (W2 @ a2): per-lane partial over 4 channels, reduce over hl
  float s2 = o0 * vs2[c0] + o1 * vs2[c0 + 1] + o2 * vs2[c0 + 2] + o3 * vs2[c0 + 3];
  float d2 = o0 * vd2[c0] + o1 * vd2[c0 + 1] + o2 * vd2[c0 + 2] + o3 * vd2[c0 + 3];
  #pragma unroll
  for (int m = 16; m; m >>= 1){ s2 += __shfl_xor(s2, m); d2 += __shfl_xor(d2, m); }
  if (lane == 0){ as2[node] = s2; ad2[node] = d2; }

  // z[node, lane] = sum_kk y[kk] * W2[kk, lane]; y[4*q+j] lives in lane q as o_j
  float zacc = 0.f;
  #pragma unroll 4
  for (int q = 0; q < 32; ++q){
    float y0 = __shfl(o0, q), y1 = __shfl(o1, q), y2 = __shfl(o2, q), y3 = __shfl(o3, q);
    const float* wr = W2 + (q * 4) * 64 + lane;
    zacc = fmaf(y0, wr[0],   zacc);
    zacc = fmaf(y1, wr[64],  zacc);
    zacc = fmaf(y2, wr[128], zacc);
    zacc = fmaf(y3, wr[192], zacc);
  }
  z[((unsigned)node << 6) + lane] = f2bf(zacc);
}

// ------- layer-2 agg: half-wave, streaming w2, ushort2 z loads -------
__global__ __launch_bounds__(256) void k_agg2(const int* __restrict__ off, const int* __restrict__ csr,
                                              const ushort* __restrict__ z, const float* __restrict__ w2,
                                              const float* __restrict__ b2, float* __restrict__ out){
  int node = blockIdx.x * 4 + (threadIdx.x >> 6);
  int lane = threadIdx.x & 63;
  int hl   = lane & 31;
  int half = lane >> 5;
  int c0   = hl * 2;
  int s0 = off[node], e0 = off[node + 1];

  float g0 = 0.f, g1 = 0.f, denp = 0.f;
  int k = s0 + half;
  for (; k + 2 < e0; k += 4){
    int sA = csr[k], sB = csr[k + 2];
    float wA = w2[k];
    float wB = w2[k + 2];
    ushort2 zA = *(const ushort2*)(z + ((unsigned)sA << 6) + c0);
    ushort2 zB = *(const ushort2*)(z + ((unsigned)sB << 6) + c0);
    denp += wA + wB;
    g0 = fmaf(wA, bf2f(zA.x), g0); g1 = fmaf(wA, bf2f(zA.y), g1);
    g0 = fmaf(wB, bf2f(zB.x), g0); g1 = fmaf(wB, bf2f(zB.y), g1);
  }
  if (k < e0){
    int sA = csr[k];
    float wA = w2[k];
    ushort2 zA = *(const ushort2*)(z + ((unsigned)sA << 6) + c0);
    denp += wA;
    g0 = fmaf(wA, bf2f(zA.x), g0); g1 = fmaf(wA, bf2f(zA.y), g1);
  }

  g0  += __shfl_xor(g0, 32);
  g1  += __shfl_xor(g1, 32);
  denp += __shfl_xor(denp, 32);

  if (half == 0){
    float inv = 1.f / (denp + 1e-16f);
    float2 o;
    o.x = elu_(g0 * inv + b2[c0]);
    o.y = elu_(g1 * inv + b2[c0 + 1]);
    *(float2*)(out + ((unsigned)node << 6) + c0) = o;
  }
}

// ---------------- host ----------------
extern "C" void kernel_launch(void* const* d_in, const int* in_sizes, int n_in,
                              void* d_out, int out_size, void* d_ws, size_t ws_size,
                              hipStream_t stream){
  const float* x      = (const float*)d_in[0];
  const int*   ei     = (const int*)d_in[1];
  const float* W1     = (const float*)d_in[2];
  const float* a_src1 = (const float*)d_in[3];
  const float* a_dst1 = (const float*)d_in[4];
  const float* b1     = (const float*)d_in[5];
  const float* W2     = (const float*)d_in[6];
  const float* a_src2 = (const float*)d_in[7];
  const float* a_dst2 = (const float*)d_in[8];
  const float* b2     = (const float*)d_in[9];
  float* out = (float*)d_out;

  // workspace (~50 MB); h1 (bf16) lives in d_out until k_agg2 overwrites it
  char* ws = (char*)d_ws;
  size_t o = 0;
  auto alloc = [&](size_t bytes){ size_t r = o; o = (o + bytes + 255) & ~(size_t)255; return r; };
  int*    tmpN = (int*)(ws + alloc((size_t)N_NODES * 4));
  int*    bs   = (int*)(ws + alloc(512));
  int*    off  = (int*)(ws + alloc((size_t)(N_NODES + 1) * 4));
  int*    csr  = (int*)(ws + alloc((size_t)TOT_E * 4));
  int*    edst = (int*)(ws + alloc((size_t)TOT_E * 4));
  float2* w1   = (float2*)(ws + alloc((size_t)TOT_E * 8));
  float*  w2   = (float*)(ws + alloc((size_t)TOT_E * 4));
  float*  as1  = (float*)(ws + alloc((size_t)N_NODES * 2 * 4));
  float*  ad1  = (float*)(ws + alloc((size_t)N_NODES * 2 * 4));
  float*  as2  = (float*)(ws + alloc((size_t)N_NODES * 4));
  float*  ad2  = (float*)(ws + alloc((size_t)N_NODES * 4));
  float*  vs2  = (float*)(ws + alloc(512));
  float*  vd2  = (float*)(ws + alloc(512));
  ushort* z    = (ushort*)(ws + alloc((size_t)N_NODES * 64 * 2));
  ushort* h1   = (ushort*)d_out;
  (void)ws_size; (void)in_sizes; (void)n_in; (void)out_size;

  const int nblk_nodes = (N_NODES + 255) / 256;
  const int nblk_edges = (TOT_E + 255) / 256;
  const int nblk_scan  = (N_NODES + 1023) / 1024;
  const int nblk_wave4 = N_NODES / 4;

  // layer-1 GEMM (+ fused alpha1) first — k_fill_w needs as1/ad1
  k_gemm1<<<(N_NODES + 127) / 128, 256, 0, stream>>>(x, W1, a_src1, a_dst1, h1, as1, ad1, N_NODES);
  k_prep2<<<1, 128, 0, stream>>>(W2, a_src2, a_dst2, vs2, vd2);

  // CSR build with fused layer-1 edge-weight computation
  k_zero  <<<nblk_nodes, 256, 0, stream>>>(tmpN, N_NODES);
  k_count <<<nblk_edges, 256, 0, stream>>>(ei, tmpN);
  k_scan1 <<<nblk_scan, 1024, 0, stream>>>(tmpN, off, bs);
  k_scan2 <<<1, 1, 0, stream>>>(bs, off, nblk_scan);
  k_scan3 <<<nblk_scan, 1024, 0, stream>>>(off, tmpN, bs);
  k_fill_w<<<nblk_edges, 256, 0, stream>>>(ei, tmpN, csr, edst, as1, ad1, w1);

  // layer-1 agg: streaming w1, fused elu + z = y@W2 + alpha2
  k_agg1 <<<nblk_wave4, 256, 0, stream>>>(off, csr, h1, (const float*)w1, b1, vs2, vd2, W2, z, as2, ad2);

  // layer-2 edge weights (slot-ordered stream), then agg2
  k_ew2  <<<nblk_edges, 256, 0, stream>>>(csr, edst, as2, ad2, w2);
  k_agg2 <<<nblk_wave4, 256, 0, stream>>>(off, csr, z, w2, b2, out);
}

// Round 8
// 584.060 us; speedup vs baseline: 1.1397x; 1.0047x over previous
//
#include <hip/hip_runtime.h>
#include <hip/hip_bf16.h>
#include <math.h>

#define N_NODES 100000
#define N_EDGES 1600000
#define TOT_E   (N_EDGES + N_NODES)

__device__ __forceinline__ float lrelu(float v){ return v > 0.f ? v : 0.2f * v; }
__device__ __forceinline__ float elu_(float v){ return v > 0.f ? v : expm1f(v); }
__device__ __forceinline__ ushort f2bf(float f){
  unsigned u = __float_as_uint(f);
  u = (u + 0x7FFFu + ((u >> 16) & 1u)) >> 16;   // RNE
  return (ushort)u;
}
__device__ __forceinline__ float bf2f(ushort u){
  return __uint_as_float(((unsigned)u) << 16);
}

// ---------------- CSR build (by dst) ----------------
__global__ __launch_bounds__(256) void k_count(const int* __restrict__ ei, int* __restrict__ cnt){
  int i = blockIdx.x * 256 + threadIdx.x;
  if (i >= TOT_E) return;
  int d = (i < N_EDGES) ? ei[N_EDGES + i] : (i - N_EDGES);
  atomicAdd(&cnt[d], 1);
}

__global__ __launch_bounds__(1024) void k_scan1(const int* __restrict__ cnt, int* __restrict__ off,
                                                int* __restrict__ bs){
  __shared__ int s[1024];
  int t = threadIdx.x;
  int i = blockIdx.x * 1024 + t;
  int v = (i < N_NODES) ? cnt[i] : 0;
  s[t] = v;
  __syncthreads();
  for (int o = 1; o < 1024; o <<= 1){
    int tmp = 0;
    if (t >= o) tmp = s[t - o];
    __syncthreads();
    if (t >= o) s[t] += tmp;
    __syncthreads();
  }
  if (i < N_NODES) off[i] = s[t] - v;
  if (t == 1023) bs[blockIdx.x] = s[1023];
}

__global__ void k_scan2(int* bs, int* off, int nb){
  if (threadIdx.x == 0 && blockIdx.x == 0){
    int base = 0;
    for (int b = 0; b < nb; ++b){ int t = bs[b]; bs[b] = base; base += t; }
    off[N_NODES] = base;
  }
}

__global__ __launch_bounds__(1024) void k_scan3(int* __restrict__ off, int* __restrict__ cur,
                                                const int* __restrict__ bs){
  int i = blockIdx.x * 1024 + threadIdx.x;
  if (i < N_NODES){
    int v = off[i] + bs[blockIdx.x];
    off[i] = v;
    cur[i] = v;
  }
}

// fill CSR + dst-per-slot + layer-1 edge weights (runs AFTER gemm1)
__global__ __launch_bounds__(256) void k_fill_w(const int* __restrict__ ei, int* __restrict__ cur,
                                                int* __restrict__ csr, int* __restrict__ edst,
                                                const float* __restrict__ as1, const float* __restrict__ ad1,
                                                float2* __restrict__ w1){
  int i = blockIdx.x * 256 + threadIdx.x;
  if (i >= TOT_E) return;
  int s, d;
  if (i < N_EDGES){ s = ei[i]; d = ei[N_EDGES + i]; }
  else            { s = d = i - N_EDGES; }
  int p = atomicAdd(&cur[d], 1);
  csr[p] = s;
  edst[p] = d;
  float2 a  = *(const float2*)(as1 + 2u * (unsigned)s);
  float2 ad = *(const float2*)(ad1 + 2u * (unsigned)d);
  float2 w;
  w.x = __expf(lrelu(a.x + ad.x));
  w.y = __expf(lrelu(a.y + ad.y));
  w1[p] = w;
}

// layer-2 edge weights (runs AFTER agg1): slot-ordered stream
__global__ __launch_bounds__(256) void k_ew2(const int* __restrict__ csr, const int* __restrict__ edst,
                                             const float* __restrict__ as2, const float* __restrict__ ad2,
                                             float* __restrict__ w2){
  int i = blockIdx.x * 256 + threadIdx.x;
  if (i >= TOT_E) return;
  w2[i] = __expf(lrelu(as2[csr[i]] + ad2[edst[i]]));
}

// ------- layer-1 GEMM fused with alpha1; h stored bf16 (in d_out) -------
__global__ __launch_bounds__(256) void k_gemm1(const float* __restrict__ x, const float* __restrict__ W,
                                               const float* __restrict__ a_src, const float* __restrict__ a_dst,
                                               ushort* __restrict__ h, float* __restrict__ as1,
                                               float* __restrict__ ad1, int n){
  const int cg   = threadIdx.x & 7;     // 8 col-groups of 16
  const int slot = threadIdx.x >> 3;    // 32 slots x 4 rows
  const int r0   = blockIdx.x * 128 + slot * 4;
  const int col0 = cg * 16;

  const float* xp[4];
  #pragma unroll
  for (int i = 0; i < 4; ++i){
    int r = r0 + i; if (r > n - 1) r = n - 1;
    xp[i] = x + (size_t)r * 128;
  }

  float acc[4][16] = {};
  const float* wp = W + col0;
  for (int k = 0; k < 128; ++k){
    float4 w0 = *(const float4*)(wp);
    float4 w1 = *(const float4*)(wp + 4);
    float4 w2 = *(const float4*)(wp + 8);
    float4 w3 = *(const float4*)(wp + 12);
    wp += 128;
    #pragma unroll
    for (int i = 0; i < 4; ++i){
      float xv = xp[i][k];
      acc[i][0]  = fmaf(xv, w0.x, acc[i][0]);  acc[i][1]  = fmaf(xv, w0.y, acc[i][1]);
      acc[i][2]  = fmaf(xv, w0.z, acc[i][2]);  acc[i][3]  = fmaf(xv, w0.w, acc[i][3]);
      acc[i][4]  = fmaf(xv, w1.x, acc[i][4]);  acc[i][5]  = fmaf(xv, w1.y, acc[i][5]);
      acc[i][6]  = fmaf(xv, w1.z, acc[i][6]);  acc[i][7]  = fmaf(xv, w1.w, acc[i][7]);
      acc[i][8]  = fmaf(xv, w2.x, acc[i][8]);  acc[i][9]  = fmaf(xv, w2.y, acc[i][9]);
      acc[i][10] = fmaf(xv, w2.z, acc[i][10]); acc[i][11] = fmaf(xv, w2.w, acc[i][11]);
      acc[i][12] = fmaf(xv, w3.x, acc[i][12]); acc[i][13] = fmaf(xv, w3.y, acc[i][13]);
      acc[i][14] = fmaf(xv, w3.z, acc[i][14]); acc[i][15] = fmaf(xv, w3.w, acc[i][15]);
    }
  }

  #pragma unroll
  for (int i = 0; i < 4; ++i){
    int r = r0 + i;
    float sp = 0.f, dp = 0.f;
    #pragma unroll
    for (int j = 0; j < 16; ++j){
      sp = fmaf(acc[i][j], a_src[col0 + j], sp);
      dp = fmaf(acc[i][j], a_dst[col0 + j], dp);
    }
    float s0 = (col0 < 64) ? sp : 0.f, s1 = (col0 < 64) ? 0.f : sp;
    float d0 = (col0 < 64) ? dp : 0.f, d1 = (col0 < 64) ? 0.f : dp;
    #pragma unroll
    for (int m = 1; m <= 4; m <<= 1){
      s0 += __shfl_xor(s0, m); s1 += __shfl_xor(s1, m);
      d0 += __shfl_xor(d0, m); d1 += __shfl_xor(d1, m);
    }
    if (r < n){
      union { uint4 q[2]; ushort us[16]; } pk;
      #pragma unroll
      for (int j = 0; j < 16; ++j) pk.us[j] = f2bf(acc[i][j]);
      uint4* dst = (uint4*)(h + (size_t)r * 128 + col0);
      dst[0] = pk.q[0]; dst[1] = pk.q[1];
      if (cg == 0){
        as1[2 * r] = s0; as1[2 * r + 1] = s1;
        ad1[2 * r] = d0; ad1[2 * r + 1] = d1;
      }
    }
  }
}

// ------- layer-2 attention vectors: vs[k] = sum_c W2[k,c]*a2[c] -------
__global__ void k_prep2(const float* __restrict__ W2, const float* __restrict__ a_src2,
                        const float* __restrict__ a_dst2, float* __restrict__ vs, float* __restrict__ vd){
  int k = threadIdx.x;  // 128 threads
  float s = 0.f, d = 0.f;
  for (int c = 0; c < 64; ++c){
    float w = W2[k * 64 + c];
    s = fmaf(w, a_src2[c], s);
    d = fmaf(w, a_dst2[c], d);
  }
  vs[k] = s; vd[k] = d;
}

// ------- layer-1 agg: half-wave loop (R4/R7 pattern) + LDS-broadcast z-GEMM -------
// Loop: lanes 0-31 even CSR slots, 32-63 odd; lane covers channels 4*hl..4*hl+3.
// Epilogue: y staged in wave-private LDS row; z = y@W2 via broadcast ds_read_b128
// (replaces 128 ds_bpermute/node with 1 ds_write + 32 ds_read).
__global__ __launch_bounds__(256) void k_agg1(const int* __restrict__ off, const int* __restrict__ csr,
                                              const ushort* __restrict__ h, const float* __restrict__ w1,
                                              const float* __restrict__ b,
                                              const float* __restrict__ vs2, const float* __restrict__ vd2,
                                              const float* __restrict__ W2,
                                              ushort* __restrict__ z, float* __restrict__ as2,
                                              float* __restrict__ ad2){
  __shared__ float yly[4][128];          // per-wave y row (wave-private, no block sync)
  int wid  = threadIdx.x >> 6;
  int node = blockIdx.x * 4 + wid;
  int lane = threadIdx.x & 63;
  int hl   = lane & 31;
  int half = lane >> 5;
  int head = hl >> 4;
  int c0   = hl * 4;
  int s0 = off[node], e0 = off[node + 1];

  float acc0 = 0.f, acc1 = 0.f, acc2 = 0.f, acc3 = 0.f, denp = 0.f;
  int k = s0 + half;
  for (; k + 2 < e0; k += 4){
    int sA = csr[k], sB = csr[k + 2];
    float wA = w1[2u * (unsigned)k + head];
    float wB = w1[2u * (unsigned)(k + 2) + head];
    ushort4 hA = *(const ushort4*)(h + ((unsigned)sA << 7) + c0);
    ushort4 hB = *(const ushort4*)(h + ((unsigned)sB << 7) + c0);
    denp += wA + wB;
    acc0 = fmaf(wA, bf2f(hA.x), acc0); acc1 = fmaf(wA, bf2f(hA.y), acc1);
    acc2 = fmaf(wA, bf2f(hA.z), acc2); acc3 = fmaf(wA, bf2f(hA.w), acc3);
    acc0 = fmaf(wB, bf2f(hB.x), acc0); acc1 = fmaf(wB, bf2f(hB.y), acc1);
    acc2 = fmaf(wB, bf2f(hB.z), acc2); acc3 = fmaf(wB, bf2f(hB.w), acc3);
  }
  if (k < e0){
    int sA = csr[k];
    float wA = w1[2u * (unsigned)k + head];
    ushort4 hA = *(const ushort4*)(h + ((unsigned)sA << 7) + c0);
    denp += wA;
    acc0 = fmaf(wA, bf2f(hA.x), acc0); acc1 = fmaf(wA, bf2f(hA.y), acc1);
    acc2 = fmaf(wA, bf2f(hA.z), acc2); acc3 = fmaf(wA, bf2f(hA.w), acc3);
  }

  // combine even/odd halves (lane <-> lane^32, same channels, same head)
  acc0 += __shfl_xor(acc0, 32); acc1 += __shfl_xor(acc1, 32);
  acc2 += __shfl_xor(acc2, 32); acc3 += __shfl_xor(acc3, 32);
  denp += __shfl_xor(denp, 32);

  float inv = 1.f / (denp + 1e-16f);
  float o0 = elu_(acc0 * inv + b[c0]);
  float o1 = elu_(acc1 * inv + b[c0 + 1]);
  float o2 = elu_(acc2 * inv + b[c0 + 2]);
  float o3 = elu_(acc3 * inv + b[c0 + 3]);

  // stage y into wave-private LDS (half 0 only; both halves hold identical o)
  if (half == 0){
    *(float4*)(&yly[wid][c0]) = make_float4(o0, o1, o2, o3);
  }

  // alpha2 = y . (W2 @ a2): per-lane partial over 4 channels, reduce over hl
  float s2 = o0 * vs2[c0] + o1 * vs2[c0 + 1] + o2 * vs2[c0 + 2] + o3 * vs2[c0 + 3];
  float d2 = o0 * vd2[c0] + o1 * vd2[c0 + 1] + o2 * vd2[c0 + 2] + o3 * vd2[c0 + 3];
  #pragma unroll
  for (int m = 16; m; m >>= 1){ s2 += __shfl_xor(s2, m); d2 += __shfl_xor(d2, m); }
  if (lane == 0){ as2[node] = s2; ad2[node] = d2; }

  // drain the ds_write (wave-private data; no block barrier needed)
  asm volatile("s_waitcnt lgkmcnt(0)" ::: "memory");

  // z[node, lane] = sum_kk y[kk] * W2[kk, lane]
  // y read 4-at-a-time via broadcast ds_read_b128 (same addr across lanes)
  float zacc = 0.f;
  const float* yw = yly[wid];
  #pragma unroll 4
  for (int q = 0; q < 32; ++q){
    float4 yv = *(const float4*)(yw + 4 * q);
    const float* wr = W2 + (q * 4) * 64 + lane;
    zacc = fmaf(yv.x, wr[0],   zacc);
    zacc = fmaf(yv.y, wr[64],  zacc);
    zacc = fmaf(yv.z, wr[128], zacc);
    zacc = fmaf(yv.w, wr[192], zacc);
  }
  z[((unsigned)node << 6) + lane] = f2bf(zacc);
}

// ------- layer-2 agg: half-wave, streaming w2, ushort2 z loads -------
__global__ __launch_bounds__(256) void k_agg2(const int* __restrict__ off, const int* __restrict__ csr,
                                              const ushort* __restrict__ z, const float* __restrict__ w2,
                                              const float* __restrict__ b2, float* __restrict__ out){
  int node = blockIdx.x * 4 + (threadIdx.x >> 6);
  int lane = threadIdx.x & 63;
  int hl   = lane & 31;
  int half = lane >> 5;
  int c0   = hl * 2;
  int s0 = off[node], e0 = off[node + 1];

  float g0 = 0.f, g1 = 0.f, denp = 0.f;
  int k = s0 + half;
  for (; k + 2 < e0; k += 4){
    int sA = csr[k], sB = csr[k + 2];
    float wA = w2[k];
    float wB = w2[k + 2];
    ushort2 zA = *(const ushort2*)(z + ((unsigned)sA << 6) + c0);
    ushort2 zB = *(const ushort2*)(z + ((unsigned)sB << 6) + c0);
    denp += wA + wB;
    g0 = fmaf(wA, bf2f(zA.x), g0); g1 = fmaf(wA, bf2f(zA.y), g1);
    g0 = fmaf(wB, bf2f(zB.x), g0); g1 = fmaf(wB, bf2f(zB.y), g1);
  }
  if (k < e0){
    int sA = csr[k];
    float wA = w2[k];
    ushort2 zA = *(const ushort2*)(z + ((unsigned)sA << 6) + c0);
    denp += wA;
    g0 = fmaf(wA, bf2f(zA.x), g0); g1 = fmaf(wA, bf2f(zA.y), g1);
  }

  g0  += __shfl_xor(g0, 32);
  g1  += __shfl_xor(g1, 32);
  denp += __shfl_xor(denp, 32);

  if (half == 0){
    float inv = 1.f / (denp + 1e-16f);
    float2 o;
    o.x = elu_(g0 * inv + b2[c0]);
    o.y = elu_(g1 * inv + b2[c0 + 1]);
    *(float2*)(out + ((unsigned)node << 6) + c0) = o;
  }
}

// ---------------- host ----------------
extern "C" void kernel_launch(void* const* d_in, const int* in_sizes, int n_in,
                              void* d_out, int out_size, void* d_ws, size_t ws_size,
                              hipStream_t stream){
  const float* x      = (const float*)d_in[0];
  const int*   ei     = (const int*)d_in[1];
  const float* W1     = (const float*)d_in[2];
  const float* a_src1 = (const float*)d_in[3];
  const float* a_dst1 = (const float*)d_in[4];
  const float* b1     = (const float*)d_in[5];
  const float* W2     = (const float*)d_in[6];
  const float* a_src2 = (const float*)d_in[7];
  const float* a_dst2 = (const float*)d_in[8];
  const float* b2     = (const float*)d_in[9];
  float* out = (float*)d_out;

  // workspace (~50 MB); h1 (bf16) lives in d_out until k_agg2 overwrites it
  char* ws = (char*)d_ws;
  size_t o = 0;
  auto alloc = [&](size_t bytes){ size_t r = o; o = (o + bytes + 255) & ~(size_t)255; return r; };
  int*    tmpN = (int*)(ws + alloc((size_t)N_NODES * 4));
  int*    bs   = (int*)(ws + alloc(512));
  int*    off  = (int*)(ws + alloc((size_t)(N_NODES + 1) * 4));
  int*    csr  = (int*)(ws + alloc((size_t)TOT_E * 4));
  int*    edst = (int*)(ws + alloc((size_t)TOT_E * 4));
  float2* w1   = (float2*)(ws + alloc((size_t)TOT_E * 8));
  float*  w2   = (float*)(ws + alloc((size_t)TOT_E * 4));
  float*  as1  = (float*)(ws + alloc((size_t)N_NODES * 2 * 4));
  float*  ad1  = (float*)(ws + alloc((size_t)N_NODES * 2 * 4));
  float*  as2  = (float*)(ws + alloc((size_t)N_NODES * 4));
  float*  ad2  = (float*)(ws + alloc((size_t)N_NODES * 4));
  float*  vs2  = (float*)(ws + alloc(512));
  float*  vd2  = (float*)(ws + alloc(512));
  ushort* z    = (ushort*)(ws + alloc((size_t)N_NODES * 64 * 2));
  ushort* h1   = (ushort*)d_out;
  (void)ws_size; (void)in_sizes; (void)n_in; (void)out_size;

  const int nblk_edges = (TOT_E + 255) / 256;
  const int nblk_scan  = (N_NODES + 1023) / 1024;
  const int nblk_wave4 = N_NODES / 4;

  // layer-1 GEMM (+ fused alpha1) first — k_fill_w needs as1/ad1
  k_gemm1<<<(N_NODES + 127) / 128, 256, 0, stream>>>(x, W1, a_src1, a_dst1, h1, as1, ad1, N_NODES);
  k_prep2<<<1, 128, 0, stream>>>(W2, a_src2, a_dst2, vs2, vd2);

  // CSR build with fused layer-1 edge-weight computation
  hipMemsetAsync(tmpN, 0, (size_t)N_NODES * 4, stream);
  k_count <<<nblk_edges, 256, 0, stream>>>(ei, tmpN);
  k_scan1 <<<nblk_scan, 1024, 0, stream>>>(tmpN, off, bs);
  k_scan2 <<<1, 1, 0, stream>>>(bs, off, nblk_scan);
  k_scan3 <<<nblk_scan, 1024, 0, stream>>>(off, tmpN, bs);
  k_fill_w<<<nblk_edges, 256, 0, stream>>>(ei, tmpN, csr, edst, as1, ad1, w1);

  // layer-1 agg: streaming w1, fused elu + z = y@W2 (LDS-broadcast) + alpha2
  k_agg1 <<<nblk_wave4, 256, 0, stream>>>(off, csr, h1, (const float*)w1, b1, vs2, vd2, W2, z, as2, ad2);

  // layer-2 edge weights (slot-ordered stream), then agg2
  k_ew2  <<<nblk_edges, 256, 0, stream>>>(csr, edst, as2, ad2, w2);
  k_agg2 <<<nblk_wave4, 256, 0, stream>>>(off, csr, z, w2, b2, out);
}

// Round 9
// 469.800 us; speedup vs baseline: 1.4168x; 1.2432x over previous
//
#include <hip/hip_runtime.h>
#include <hip/hip_bf16.h>
#include <math.h>

#define N_NODES 100000
#define N_EDGES 1600000
#define TOT_E   (N_EDGES + N_NODES)

__device__ __forceinline__ float lrelu(float v){ return v > 0.f ? v : 0.2f * v; }
__device__ __forceinline__ float elu_(float v){ return v > 0.f ? v : expm1f(v); }
__device__ __forceinline__ ushort f2bf(float f){
  unsigned u = __float_as_uint(f);
  u = (u + 0x7FFFu + ((u >> 16) & 1u)) >> 16;   // RNE
  return (ushort)u;
}
__device__ __forceinline__ float bf2f(ushort u){
  return __uint_as_float(((unsigned)u) << 16);
}

// ---------------- CSR build (by dst) ----------------
__global__ __launch_bounds__(256) void k_count(const int* __restrict__ ei, int* __restrict__ cnt){
  int i = blockIdx.x * 256 + threadIdx.x;
  if (i >= TOT_E) return;
  int d = (i < N_EDGES) ? ei[N_EDGES + i] : (i - N_EDGES);
  atomicAdd(&cnt[d], 1);
}

__global__ __launch_bounds__(1024) void k_scan1(const int* __restrict__ cnt, int* __restrict__ off,
                                                int* __restrict__ bs){
  __shared__ int s[1024];
  int t = threadIdx.x;
  int i = blockIdx.x * 1024 + t;
  int v = (i < N_NODES) ? cnt[i] : 0;
  s[t] = v;
  __syncthreads();
  for (int o = 1; o < 1024; o <<= 1){
    int tmp = 0;
    if (t >= o) tmp = s[t - o];
    __syncthreads();
    if (t >= o) s[t] += tmp;
    __syncthreads();
  }
  if (i < N_NODES) off[i] = s[t] - v;
  if (t == 1023) bs[blockIdx.x] = s[1023];
}

__global__ void k_scan2(int* bs, int* off, int nb){
  if (threadIdx.x == 0 && blockIdx.x == 0){
    int base = 0;
    for (int b = 0; b < nb; ++b){ int t = bs[b]; bs[b] = base; base += t; }
    off[N_NODES] = base;
  }
}

__global__ __launch_bounds__(1024) void k_scan3(int* __restrict__ off, int* __restrict__ cur,
                                                const int* __restrict__ bs){
  int i = blockIdx.x * 1024 + threadIdx.x;
  if (i < N_NODES){
    int v = off[i] + bs[blockIdx.x];
    off[i] = v;
    cur[i] = v;
  }
}

// fill CSR + dst-per-slot + layer-1 edge weights (runs AFTER gemm1)
__global__ __launch_bounds__(256) void k_fill_w(const int* __restrict__ ei, int* __restrict__ cur,
                                                int* __restrict__ csr, int* __restrict__ edst,
                                                const float* __restrict__ as1, const float* __restrict__ ad1,
                                                float2* __restrict__ w1){
  int i = blockIdx.x * 256 + threadIdx.x;
  if (i >= TOT_E) return;
  int s, d;
  if (i < N_EDGES){ s = ei[i]; d = ei[N_EDGES + i]; }
  else            { s = d = i - N_EDGES; }
  int p = atomicAdd(&cur[d], 1);
  csr[p] = s;
  edst[p] = d;
  float2 a  = *(const float2*)(as1 + 2u * (unsigned)s);
  float2 ad = *(const float2*)(ad1 + 2u * (unsigned)d);
  float2 w;
  w.x = __expf(lrelu(a.x + ad.x));
  w.y = __expf(lrelu(a.y + ad.y));
  w1[p] = w;
}

// layer-2 edge weights (runs AFTER agg1): slot-ordered stream
__global__ __launch_bounds__(256) void k_ew2(const int* __restrict__ csr, const int* __restrict__ edst,
                                             const float* __restrict__ as2, const float* __restrict__ ad2,
                                             float* __restrict__ w2){
  int i = blockIdx.x * 256 + threadIdx.x;
  if (i >= TOT_E) return;
  w2[i] = __expf(lrelu(as2[csr[i]] + ad2[edst[i]]));
}

// ------- layer-1 GEMM (LDS-staged) fused with alpha1; h stored bf16 (in d_out) -------
// 128-row tile, k-chunked by 32; x chunk and W chunk staged in LDS.
// Thread (slot=tid>>3 in 0..31, cg=tid&7): 4 rows (slot*4..+3), 16 cols (cg*16..+15).
__global__ __launch_bounds__(256) void k_gemm1(const float* __restrict__ x, const float* __restrict__ W,
                                               const float* __restrict__ a_src, const float* __restrict__ a_dst,
                                               ushort* __restrict__ h, float* __restrict__ as1,
                                               float* __restrict__ ad1, int n){
  __shared__ float sx[128][36];   // 128 rows x 32 k (pad 36: rows 4 banks apart, 16B aligned)
  __shared__ float sw[32][132];   // 32 k x 128 cols (pad 132: 16B aligned)
  const int tid  = threadIdx.x;
  const int cg   = tid & 7;
  const int slot = tid >> 3;
  const int rbase = blockIdx.x * 128;
  const int r0   = rbase + slot * 4;
  const int col0 = cg * 16;

  float acc[4][16] = {};

  for (int kc = 0; kc < 4; ++kc){
    __syncthreads();                     // previous chunk's reads complete
    // stage x chunk: rows rbase..rbase+127, k in [kc*32, kc*32+32)
    #pragma unroll
    for (int i = 0; i < 4; ++i){
      int f   = tid + 256 * i;           // 0..1023 float4s
      int row = f >> 3;                  // 8 float4 per row
      int c4  = f & 7;
      int gr  = rbase + row; if (gr > n - 1) gr = n - 1;
      float4 v = *(const float4*)(x + (size_t)gr * 128 + kc * 32 + c4 * 4);
      *(float4*)(&sx[row][c4 * 4]) = v;
    }
    // stage W chunk: k in [kc*32, kc*32+32), all 128 cols
    #pragma unroll
    for (int i = 0; i < 4; ++i){
      int f  = tid + 256 * i;            // 0..1023 float4s
      int k  = f >> 5;                   // 32 float4 per k-row
      int c4 = f & 31;
      float4 v = *(const float4*)(W + (size_t)(kc * 32 + k) * 128 + c4 * 4);
      *(float4*)(&sw[k][c4 * 4]) = v;
    }
    __syncthreads();

    #pragma unroll 8
    for (int j = 0; j < 32; ++j){
      float4 w0 = *(const float4*)(&sw[j][col0]);
      float4 w1 = *(const float4*)(&sw[j][col0 + 4]);
      float4 w2 = *(const float4*)(&sw[j][col0 + 8]);
      float4 w3 = *(const float4*)(&sw[j][col0 + 12]);
      #pragma unroll
      for (int i = 0; i < 4; ++i){
        float xv = sx[slot * 4 + i][j];
        acc[i][0]  = fmaf(xv, w0.x, acc[i][0]);  acc[i][1]  = fmaf(xv, w0.y, acc[i][1]);
        acc[i][2]  = fmaf(xv, w0.z, acc[i][2]);  acc[i][3]  = fmaf(xv, w0.w, acc[i][3]);
        acc[i][4]  = fmaf(xv, w1.x, acc[i][4]);  acc[i][5]  = fmaf(xv, w1.y, acc[i][5]);
        acc[i][6]  = fmaf(xv, w1.z, acc[i][6]);  acc[i][7]  = fmaf(xv, w1.w, acc[i][7]);
        acc[i][8]  = fmaf(xv, w2.x, acc[i][8]);  acc[i][9]  = fmaf(xv, w2.y, acc[i][9]);
        acc[i][10] = fmaf(xv, w2.z, acc[i][10]); acc[i][11] = fmaf(xv, w2.w, acc[i][11]);
        acc[i][12] = fmaf(xv, w3.x, acc[i][12]); acc[i][13] = fmaf(xv, w3.y, acc[i][13]);
        acc[i][14] = fmaf(xv, w3.z, acc[i][14]); acc[i][15] = fmaf(xv, w3.w, acc[i][15]);
      }
    }
  }

  #pragma unroll
  for (int i = 0; i < 4; ++i){
    int r = r0 + i;
    float sp = 0.f, dp = 0.f;
    #pragma unroll
    for (int j = 0; j < 16; ++j){
      sp = fmaf(acc[i][j], a_src[col0 + j], sp);
      dp = fmaf(acc[i][j], a_dst[col0 + j], dp);
    }
    float s0 = (col0 < 64) ? sp : 0.f, s1 = (col0 < 64) ? 0.f : sp;
    float d0 = (col0 < 64) ? dp : 0.f, d1 = (col0 < 64) ? 0.f : dp;
    #pragma unroll
    for (int m = 1; m <= 4; m <<= 1){
      s0 += __shfl_xor(s0, m); s1 += __shfl_xor(s1, m);
      d0 += __shfl_xor(d0, m); d1 += __shfl_xor(d1, m);
    }
    if (r < n){
      union { uint4 q[2]; ushort us[16]; } pk;
      #pragma unroll
      for (int j = 0; j < 16; ++j) pk.us[j] = f2bf(acc[i][j]);
      uint4* dst = (uint4*)(h + (size_t)r * 128 + col0);
      dst[0] = pk.q[0]; dst[1] = pk.q[1];
      if (cg == 0){
        as1[2 * r] = s0; as1[2 * r + 1] = s1;
        ad1[2 * r] = d0; ad1[2 * r + 1] = d1;
      }
    }
  }
}

// ------- layer-2 attention vectors: vs[k] = sum_c W2[k,c]*a2[c] -------
__global__ void k_prep2(const float* __restrict__ W2, const float* __restrict__ a_src2,
                        const float* __restrict__ a_dst2, float* __restrict__ vs, float* __restrict__ vd){
  int k = threadIdx.x;  // 128 threads
  float s = 0.f, d = 0.f;
  for (int c = 0; c < 64; ++c){
    float w = W2[k * 64 + c];
    s = fmaf(w, a_src2[c], s);
    d = fmaf(w, a_dst2[c], d);
  }
  vs[k] = s; vd[k] = d;
}

// ------- layer-1 agg: half-wave, 4-edge unroll (8 gathers in flight) -------
// lanes 0-31 even CSR slots, 32-63 odd; lane covers channels 4*hl..4*hl+3.
// Epilogue: LDS-broadcast z = y@W2 + alpha2.
__global__ __launch_bounds__(256) void k_agg1(const int* __restrict__ off, const int* __restrict__ csr,
                                              const ushort* __restrict__ h, const float* __restrict__ w1,
                                              const float* __restrict__ b,
                                              const float* __restrict__ vs2, const float* __restrict__ vd2,
                                              const float* __restrict__ W2,
                                              ushort* __restrict__ z, float* __restrict__ as2,
                                              float* __restrict__ ad2){
  __shared__ float yly[4][128];          // per-wave y row (wave-private)
  int wid  = threadIdx.x >> 6;
  int node = blockIdx.x * 4 + wid;
  int lane = threadIdx.x & 63;
  int hl   = lane & 31;
  int half = lane >> 5;
  int head = hl >> 4;
  int c0   = hl * 4;
  int s0 = off[node], e0 = off[node + 1];

  float acc0 = 0.f, acc1 = 0.f, acc2 = 0.f, acc3 = 0.f, denp = 0.f;
  int k = s0 + half;
  for (; k + 6 < e0; k += 8){            // 4 edges per half per iter
    int sA = csr[k],     sB = csr[k + 2];
    int sC = csr[k + 4], sD = csr[k + 6];
    float wA = w1[2u * (unsigned)k + head];
    float wB = w1[2u * (unsigned)(k + 2) + head];
    float wC = w1[2u * (unsigned)(k + 4) + head];
    float wD = w1[2u * (unsigned)(k + 6) + head];
    ushort4 hA = *(const ushort4*)(h + ((unsigned)sA << 7) + c0);
    ushort4 hB = *(const ushort4*)(h + ((unsigned)sB << 7) + c0);
    ushort4 hC = *(const ushort4*)(h + ((unsigned)sC << 7) + c0);
    ushort4 hD = *(const ushort4*)(h + ((unsigned)sD << 7) + c0);
    denp += (wA + wB) + (wC + wD);
    acc0 = fmaf(wA, bf2f(hA.x), acc0); acc1 = fmaf(wA, bf2f(hA.y), acc1);
    acc2 = fmaf(wA, bf2f(hA.z), acc2); acc3 = fmaf(wA, bf2f(hA.w), acc3);
    acc0 = fmaf(wB, bf2f(hB.x), acc0); acc1 = fmaf(wB, bf2f(hB.y), acc1);
    acc2 = fmaf(wB, bf2f(hB.z), acc2); acc3 = fmaf(wB, bf2f(hB.w), acc3);
    acc0 = fmaf(wC, bf2f(hC.x), acc0); acc1 = fmaf(wC, bf2f(hC.y), acc1);
    acc2 = fmaf(wC, bf2f(hC.z), acc2); acc3 = fmaf(wC, bf2f(hC.w), acc3);
    acc0 = fmaf(wD, bf2f(hD.x), acc0); acc1 = fmaf(wD, bf2f(hD.y), acc1);
    acc2 = fmaf(wD, bf2f(hD.z), acc2); acc3 = fmaf(wD, bf2f(hD.w), acc3);
  }
  for (; k < e0; k += 2){
    int sA = csr[k];
    float wA = w1[2u * (unsigned)k + head];
    ushort4 hA = *(const ushort4*)(h + ((unsigned)sA << 7) + c0);
    denp += wA;
    acc0 = fmaf(wA, bf2f(hA.x), acc0); acc1 = fmaf(wA, bf2f(hA.y), acc1);
    acc2 = fmaf(wA, bf2f(hA.z), acc2); acc3 = fmaf(wA, bf2f(hA.w), acc3);
  }

  // combine even/odd halves (lane <-> lane^32, same channels, same head)
  acc0 += __shfl_xor(acc0, 32); acc1 += __shfl_xor(acc1, 32);
  acc2 += __shfl_xor(acc2, 32); acc3 += __shfl_xor(acc3, 32);
  denp += __shfl_xor(denp, 32);

  float inv = 1.f / (denp + 1e-16f);
  float o0 = elu_(acc0 * inv + b[c0]);
  float o1 = elu_(acc1 * inv + b[c0 + 1]);
  float o2 = elu_(acc2 * inv + b[c0 + 2]);
  float o3 = elu_(acc3 * inv + b[c0 + 3]);

  // stage y into wave-private LDS (half 0 only; both halves hold identical o)
  if (half == 0){
    *(float4*)(&yly[wid][c0]) = make_float4(o0, o1, o2, o3);
  }

  // alpha2 = y . (W2 @ a2): per-lane partial over 4 channels, reduce over hl
  float s2 = o0 * vs2[c0] + o1 * vs2[c0 + 1] + o2 * vs2[c0 + 2] + o3 * vs2[c0 + 3];
  float d2 = o0 * vd2[c0] + o1 * vd2[c0 + 1] + o2 * vd2[c0 + 2] + o3 * vd2[c0 + 3];
  #pragma unroll
  for (int m = 16; m; m >>= 1){ s2 += __shfl_xor(s2, m); d2 += __shfl_xor(d2, m); }
  if (lane == 0){ as2[node] = s2; ad2[node] = d2; }

  // drain the ds_write (wave-private data; no block barrier needed)
  asm volatile("s_waitcnt lgkmcnt(0)" ::: "memory");

  // z[node, lane] = sum_kk y[kk] * W2[kk, lane] via broadcast ds_read_b128
  float zacc = 0.f;
  const float* yw = yly[wid];
  #pragma unroll 4
  for (int q = 0; q < 32; ++q){
    float4 yv = *(const float4*)(yw + 4 * q);
    const float* wr = W2 + (q * 4) * 64 + lane;
    zacc = fmaf(yv.x, wr[0],   zacc);
    zacc = fmaf(yv.y, wr[64],  zacc);
    zacc = fmaf(yv.z, wr[128], zacc);
    zacc = fmaf(yv.w, wr[192], zacc);
  }
  z[((unsigned)node << 6) + lane] = f2bf(zacc);
}

// ------- layer-2 agg: half-wave, 4-edge unroll, streaming w2 -------
__global__ __launch_bounds__(256) void k_agg2(const int* __restrict__ off, const int* __restrict__ csr,
                                              const ushort* __restrict__ z, const float* __restrict__ w2,
                                              const float* __restrict__ b2, float* __restrict__ out){
  int node = blockIdx.x * 4 + (threadIdx.x >> 6);
  int lane = threadIdx.x & 63;
  int hl   = lane & 31;
  int half = lane >> 5;
  int c0   = hl * 2;
  int s0 = off[node], e0 = off[node + 1];

  float g0 = 0.f, g1 = 0.f, denp = 0.f;
  int k = s0 + half;
  for (; k + 6 < e0; k += 8){
    int sA = csr[k],     sB = csr[k + 2];
    int sC = csr[k + 4], sD = csr[k + 6];
    float wA = w2[k],     wB = w2[k + 2];
    float wC = w2[k + 4], wD = w2[k + 6];
    ushort2 zA = *(const ushort2*)(z + ((unsigned)sA << 6) + c0);
    ushort2 zB = *(const ushort2*)(z + ((unsigned)sB << 6) + c0);
    ushort2 zC = *(const ushort2*)(z + ((unsigned)sC << 6) + c0);
    ushort2 zD = *(const ushort2*)(z + ((unsigned)sD << 6) + c0);
    denp += (wA + wB) + (wC + wD);
    g0 = fmaf(wA, bf2f(zA.x), g0); g1 = fmaf(wA, bf2f(zA.y), g1);
    g0 = fmaf(wB, bf2f(zB.x), g0); g1 = fmaf(wB, bf2f(zB.y), g1);
    g0 = fmaf(wC, bf2f(zC.x), g0); g1 = fmaf(wC, bf2f(zC.y), g1);
    g0 = fmaf(wD, bf2f(zD.x), g0); g1 = fmaf(wD, bf2f(zD.y), g1);
  }
  for (; k < e0; k += 2){
    int sA = csr[k];
    float wA = w2[k];
    ushort2 zA = *(const ushort2*)(z + ((unsigned)sA << 6) + c0);
    denp += wA;
    g0 = fmaf(wA, bf2f(zA.x), g0); g1 = fmaf(wA, bf2f(zA.y), g1);
  }

  g0  += __shfl_xor(g0, 32);
  g1  += __shfl_xor(g1, 32);
  denp += __shfl_xor(denp, 32);

  if (half == 0){
    float inv = 1.f / (denp + 1e-16f);
    float2 o;
    o.x = elu_(g0 * inv + b2[c0]);
    o.y = elu_(g1 * inv + b2[c0 + 1]);
    *(float2*)(out + ((unsigned)node << 6) + c0) = o;
  }
}

// ---------------- host ----------------
extern "C" void kernel_launch(void* const* d_in, const int* in_sizes, int n_in,
                              void* d_out, int out_size, void* d_ws, size_t ws_size,
                              hipStream_t stream){
  const float* x      = (const float*)d_in[0];
  const int*   ei     = (const int*)d_in[1];
  const float* W1     = (const float*)d_in[2];
  const float* a_src1 = (const float*)d_in[3];
  const float* a_dst1 = (const float*)d_in[4];
  const float* b1     = (const float*)d_in[5];
  const float* W2     = (const float*)d_in[6];
  const float* a_src2 = (const float*)d_in[7];
  const float* a_dst2 = (const float*)d_in[8];
  const float* b2     = (const float*)d_in[9];
  float* out = (float*)d_out;

  // workspace (~50 MB); h1 (bf16) lives in d_out until k_agg2 overwrites it
  char* ws = (char*)d_ws;
  size_t o = 0;
  auto alloc = [&](size_t bytes){ size_t r = o; o = (o + bytes + 255) & ~(size_t)255; return r; };
  int*    tmpN = (int*)(ws + alloc((size_t)N_NODES * 4));
  int*    bs   = (int*)(ws + alloc(512));
  int*    off  = (int*)(ws + alloc((size_t)(N_NODES + 1) * 4));
  int*    csr  = (int*)(ws + alloc((size_t)TOT_E * 4));
  int*    edst = (int*)(ws + alloc((size_t)TOT_E * 4));
  float2* w1   = (float2*)(ws + alloc((size_t)TOT_E * 8));
  float*  w2   = (float*)(ws + alloc((size_t)TOT_E * 4));
  float*  as1  = (float*)(ws + alloc((size_t)N_NODES * 2 * 4));
  float*  ad1  = (float*)(ws + alloc((size_t)N_NODES * 2 * 4));
  float*  as2  = (float*)(ws + alloc((size_t)N_NODES * 4));
  float*  ad2  = (float*)(ws + alloc((size_t)N_NODES * 4));
  float*  vs2  = (float*)(ws + alloc(512));
  float*  vd2  = (float*)(ws + alloc(512));
  ushort* z    = (ushort*)(ws + alloc((size_t)N_NODES * 64 * 2));
  ushort* h1   = (ushort*)d_out;
  (void)ws_size; (void)in_sizes; (void)n_in; (void)out_size;

  const int nblk_edges = (TOT_E + 255) / 256;
  const int nblk_scan  = (N_NODES + 1023) / 1024;
  const int nblk_wave4 = N_NODES / 4;

  // layer-1 GEMM (+ fused alpha1) first — k_fill_w needs as1/ad1
  k_gemm1<<<(N_NODES + 127) / 128, 256, 0, stream>>>(x, W1, a_src1, a_dst1, h1, as1, ad1, N_NODES);
  k_prep2<<<1, 128, 0, stream>>>(W2, a_src2, a_dst2, vs2, vd2);

  // CSR build with fused layer-1 edge-weight computation
  hipMemsetAsync(tmpN, 0, (size_t)N_NODES * 4, stream);
  k_count <<<nblk_edges, 256, 0, stream>>>(ei, tmpN);
  k_scan1 <<<nblk_scan, 1024, 0, stream>>>(tmpN, off, bs);
  k_scan2 <<<1, 1, 0, stream>>>(bs, off, nblk_scan);
  k_scan3 <<<nblk_scan, 1024, 0, stream>>>(off, tmpN, bs);
  k_fill_w<<<nblk_edges, 256, 0, stream>>>(ei, tmpN, csr, edst, as1, ad1, w1);

  // layer-1 agg: streaming w1, fused elu + z = y@W2 (LDS-broadcast) + alpha2
  k_agg1 <<<nblk_wave4, 256, 0, stream>>>(off, csr, h1, (const float*)w1, b1, vs2, vd2, W2, z, as2, ad2);

  // layer-2 edge weights (slot-ordered stream), then agg2
  k_ew2  <<<nblk_edges, 256, 0, stream>>>(csr, edst, as2, ad2, w2);
  k_agg2 <<<nblk_wave4, 256, 0, stream>>>(off, csr, z, w2, b2, out);
}

// Round 10
// 466.474 us; speedup vs baseline: 1.4269x; 1.0071x over previous
//
#include <hip/hip_runtime.h>
#include <hip/hip_bf16.h>
#include <math.h>

#define N_NODES 100000
#define N_EDGES 1600000
#define TOT_E   (N_EDGES + N_NODES)

__device__ __forceinline__ float lrelu(float v){ return v > 0.f ? v : 0.2f * v; }
__device__ __forceinline__ float elu_(float v){ return v > 0.f ? v : expm1f(v); }
__device__ __forceinline__ ushort f2bf(float f){
  unsigned u = __float_as_uint(f);
  u = (u + 0x7FFFu + ((u >> 16) & 1u)) >> 16;   // RNE
  return (ushort)u;
}
__device__ __forceinline__ float bf2f(ushort u){
  return __uint_as_float(((unsigned)u) << 16);
}

// ---------------- CSR build (by dst) ----------------
__global__ __launch_bounds__(256) void k_count(const int* __restrict__ ei, int* __restrict__ cnt){
  int i = blockIdx.x * 256 + threadIdx.x;
  if (i >= TOT_E) return;
  int d = (i < N_EDGES) ? ei[N_EDGES + i] : (i - N_EDGES);
  atomicAdd(&cnt[d], 1);
}

__global__ __launch_bounds__(1024) void k_scan1(const int* __restrict__ cnt, int* __restrict__ off,
                                                int* __restrict__ bs){
  __shared__ int s[1024];
  int t = threadIdx.x;
  int i = blockIdx.x * 1024 + t;
  int v = (i < N_NODES) ? cnt[i] : 0;
  s[t] = v;
  __syncthreads();
  for (int o = 1; o < 1024; o <<= 1){
    int tmp = 0;
    if (t >= o) tmp = s[t - o];
    __syncthreads();
    if (t >= o) s[t] += tmp;
    __syncthreads();
  }
  if (i < N_NODES) off[i] = s[t] - v;
  if (t == 1023) bs[blockIdx.x] = s[1023];
}

// parallel scan of the 98 block sums (was a serial single-thread loop)
__global__ __launch_bounds__(128) void k_scan2(int* __restrict__ bs, int* __restrict__ off, int nb){
  __shared__ int s[128];
  int t = threadIdx.x;
  int v = (t < nb) ? bs[t] : 0;
  s[t] = v;
  __syncthreads();
  #pragma unroll
  for (int o = 1; o < 128; o <<= 1){
    int tmp = 0;
    if (t >= o) tmp = s[t - o];
    __syncthreads();
    if (t >= o) s[t] += tmp;
    __syncthreads();
  }
  if (t < nb) bs[t] = s[t] - v;            // exclusive prefix
  if (t == nb - 1) off[N_NODES] = s[t];    // grand total
}

__global__ __launch_bounds__(1024) void k_scan3(int* __restrict__ off, int* __restrict__ cur,
                                                const int* __restrict__ bs){
  int i = blockIdx.x * 1024 + threadIdx.x;
  if (i < N_NODES){
    int v = off[i] + bs[blockIdx.x];
    off[i] = v;
    cur[i] = v;
  }
}

// fill packed CSR {src, w_head0, w_head1, dst} (runs AFTER gemm1)
__global__ __launch_bounds__(256) void k_fill_w(const int* __restrict__ ei, int* __restrict__ cur,
                                                uint4* __restrict__ csr4,
                                                const float* __restrict__ as1, const float* __restrict__ ad1){
  int i = blockIdx.x * 256 + threadIdx.x;
  if (i >= TOT_E) return;
  int s, d;
  if (i < N_EDGES){ s = ei[i]; d = ei[N_EDGES + i]; }
  else            { s = d = i - N_EDGES; }
  int p = atomicAdd(&cur[d], 1);
  float2 a  = *(const float2*)(as1 + 2u * (unsigned)s);
  float2 ad = *(const float2*)(ad1 + 2u * (unsigned)d);
  uint4 v;
  v.x = (unsigned)s;
  v.y = __float_as_uint(__expf(lrelu(a.x + ad.x)));
  v.z = __float_as_uint(__expf(lrelu(a.y + ad.y)));
  v.w = (unsigned)d;
  csr4[p] = v;
}

// layer-2 packed edge records {src, w2} (runs AFTER agg1)
__global__ __launch_bounds__(256) void k_ew2(const uint4* __restrict__ csr4,
                                             const float* __restrict__ as2, const float* __restrict__ ad2,
                                             uint2* __restrict__ ew){
  int i = blockIdx.x * 256 + threadIdx.x;
  if (i >= TOT_E) return;
  uint4 v = csr4[i];
  float w = __expf(lrelu(as2[v.x] + ad2[v.w]));
  ew[i] = make_uint2(v.x, __float_as_uint(w));
}

// ------- layer-1 GEMM (LDS-staged) fused with alpha1; h stored bf16 (in d_out) -------
__global__ __launch_bounds__(256) void k_gemm1(const float* __restrict__ x, const float* __restrict__ W,
                                               const float* __restrict__ a_src, const float* __restrict__ a_dst,
                                               ushort* __restrict__ h, float* __restrict__ as1,
                                               float* __restrict__ ad1, int n){
  __shared__ float sx[128][36];
  __shared__ float sw[32][132];
  const int tid  = threadIdx.x;
  const int cg   = tid & 7;
  const int slot = tid >> 3;
  const int rbase = blockIdx.x * 128;
  const int r0   = rbase + slot * 4;
  const int col0 = cg * 16;

  float acc[4][16] = {};

  for (int kc = 0; kc < 4; ++kc){
    __syncthreads();
    #pragma unroll
    for (int i = 0; i < 4; ++i){
      int f   = tid + 256 * i;
      int row = f >> 3;
      int c4  = f & 7;
      int gr  = rbase + row; if (gr > n - 1) gr = n - 1;
      float4 v = *(const float4*)(x + (size_t)gr * 128 + kc * 32 + c4 * 4);
      *(float4*)(&sx[row][c4 * 4]) = v;
    }
    #pragma unroll
    for (int i = 0; i < 4; ++i){
      int f  = tid + 256 * i;
      int k  = f >> 5;
      int c4 = f & 31;
      float4 v = *(const float4*)(W + (size_t)(kc * 32 + k) * 128 + c4 * 4);
      *(float4*)(&sw[k][c4 * 4]) = v;
    }
    __syncthreads();

    #pragma unroll 8
    for (int j = 0; j < 32; ++j){
      float4 w0 = *(const float4*)(&sw[j][col0]);
      float4 w1 = *(const float4*)(&sw[j][col0 + 4]);
      float4 w2 = *(const float4*)(&sw[j][col0 + 8]);
      float4 w3 = *(const float4*)(&sw[j][col0 + 12]);
      #pragma unroll
      for (int i = 0; i < 4; ++i){
        float xv = sx[slot * 4 + i][j];
        acc[i][0]  = fmaf(xv, w0.x, acc[i][0]);  acc[i][1]  = fmaf(xv, w0.y, acc[i][1]);
        acc[i][2]  = fmaf(xv, w0.z, acc[i][2]);  acc[i][3]  = fmaf(xv, w0.w, acc[i][3]);
        acc[i][4]  = fmaf(xv, w1.x, acc[i][4]);  acc[i][5]  = fmaf(xv, w1.y, acc[i][5]);
        acc[i][6]  = fmaf(xv, w1.z, acc[i][6]);  acc[i][7]  = fmaf(xv, w1.w, acc[i][7]);
        acc[i][8]  = fmaf(xv, w2.x, acc[i][8]);  acc[i][9]  = fmaf(xv, w2.y, acc[i][9]);
        acc[i][10] = fmaf(xv, w2.z, acc[i][10]); acc[i][11] = fmaf(xv, w2.w, acc[i][11]);
        acc[i][12] = fmaf(xv, w3.x, acc[i][12]); acc[i][13] = fmaf(xv, w3.y, acc[i][13]);
        acc[i][14] = fmaf(xv, w3.z, acc[i][14]); acc[i][15] = fmaf(xv, w3.w, acc[i][15]);
      }
    }
  }

  #pragma unroll
  for (int i = 0; i < 4; ++i){
    int r = r0 + i;
    float sp = 0.f, dp = 0.f;
    #pragma unroll
    for (int j = 0; j < 16; ++j){
      sp = fmaf(acc[i][j], a_src[col0 + j], sp);
      dp = fmaf(acc[i][j], a_dst[col0 + j], dp);
    }
    float s0 = (col0 < 64) ? sp : 0.f, s1 = (col0 < 64) ? 0.f : sp;
    float d0 = (col0 < 64) ? dp : 0.f, d1 = (col0 < 64) ? 0.f : dp;
    #pragma unroll
    for (int m = 1; m <= 4; m <<= 1){
      s0 += __shfl_xor(s0, m); s1 += __shfl_xor(s1, m);
      d0 += __shfl_xor(d0, m); d1 += __shfl_xor(d1, m);
    }
    if (r < n){
      union { uint4 q[2]; ushort us[16]; } pk;
      #pragma unroll
      for (int j = 0; j < 16; ++j) pk.us[j] = f2bf(acc[i][j]);
      uint4* dst = (uint4*)(h + (size_t)r * 128 + col0);
      dst[0] = pk.q[0]; dst[1] = pk.q[1];
      if (cg == 0){
        as1[2 * r] = s0; as1[2 * r + 1] = s1;
        ad1[2 * r] = d0; ad1[2 * r + 1] = d1;
      }
    }
  }
}

// ------- layer-2 attention vectors: vs[k] = sum_c W2[k,c]*a2[c] -------
__global__ void k_prep2(const float* __restrict__ W2, const float* __restrict__ a_src2,
                        const float* __restrict__ a_dst2, float* __restrict__ vs, float* __restrict__ vd){
  int k = threadIdx.x;  // 128 threads
  float s = 0.f, d = 0.f;
  for (int c = 0; c < 64; ++c){
    float w = W2[k * 64 + c];
    s = fmaf(w, a_src2[c], s);
    d = fmaf(w, a_dst2[c], d);
  }
  vs[k] = s; vd[k] = d;
}

// ------- layer-1 agg: half-wave, 4-edge unroll, packed csr4 (1 load/edge) -------
__global__ __launch_bounds__(256) void k_agg1(const int* __restrict__ off, const uint4* __restrict__ csr4,
                                              const ushort* __restrict__ h,
                                              const float* __restrict__ b,
                                              const float* __restrict__ vs2, const float* __restrict__ vd2,
                                              const float* __restrict__ W2,
                                              ushort* __restrict__ z, float* __restrict__ as2,
                                              float* __restrict__ ad2){
  __shared__ float yly[4][128];          // per-wave y row (wave-private)
  int wid  = threadIdx.x >> 6;
  int node = blockIdx.x * 4 + wid;
  int lane = threadIdx.x & 63;
  int hl   = lane & 31;
  int half = lane >> 5;
  int head = hl >> 4;
  int c0   = hl * 4;
  int s0 = off[node], e0 = off[node + 1];

  float acc0 = 0.f, acc1 = 0.f, acc2 = 0.f, acc3 = 0.f, denp = 0.f;
  int k = s0 + half;
  for (; k + 6 < e0; k += 8){            // 4 edges per half per iter
    uint4 eA = csr4[k],     eB = csr4[k + 2];
    uint4 eC = csr4[k + 4], eD = csr4[k + 6];
    ushort4 hA = *(const ushort4*)(h + ((size_t)eA.x << 7) + c0);
    ushort4 hB = *(const ushort4*)(h + ((size_t)eB.x << 7) + c0);
    ushort4 hC = *(const ushort4*)(h + ((size_t)eC.x << 7) + c0);
    ushort4 hD = *(const ushort4*)(h + ((size_t)eD.x << 7) + c0);
    float wA = __uint_as_float(head ? eA.z : eA.y);
    float wB = __uint_as_float(head ? eB.z : eB.y);
    float wC = __uint_as_float(head ? eC.z : eC.y);
    float wD = __uint_as_float(head ? eD.z : eD.y);
    denp += (wA + wB) + (wC + wD);
    acc0 = fmaf(wA, bf2f(hA.x), acc0); acc1 = fmaf(wA, bf2f(hA.y), acc1);
    acc2 = fmaf(wA, bf2f(hA.z), acc2); acc3 = fmaf(wA, bf2f(hA.w), acc3);
    acc0 = fmaf(wB, bf2f(hB.x), acc0); acc1 = fmaf(wB, bf2f(hB.y), acc1);
    acc2 = fmaf(wB, bf2f(hB.z), acc2); acc3 = fmaf(wB, bf2f(hB.w), acc3);
    acc0 = fmaf(wC, bf2f(hC.x), acc0); acc1 = fmaf(wC, bf2f(hC.y), acc1);
    acc2 = fmaf(wC, bf2f(hC.z), acc2); acc3 = fmaf(wC, bf2f(hC.w), acc3);
    acc0 = fmaf(wD, bf2f(hD.x), acc0); acc1 = fmaf(wD, bf2f(hD.y), acc1);
    acc2 = fmaf(wD, bf2f(hD.z), acc2); acc3 = fmaf(wD, bf2f(hD.w), acc3);
  }
  for (; k < e0; k += 2){
    uint4 eA = csr4[k];
    ushort4 hA = *(const ushort4*)(h + ((size_t)eA.x << 7) + c0);
    float wA = __uint_as_float(head ? eA.z : eA.y);
    denp += wA;
    acc0 = fmaf(wA, bf2f(hA.x), acc0); acc1 = fmaf(wA, bf2f(hA.y), acc1);
    acc2 = fmaf(wA, bf2f(hA.z), acc2); acc3 = fmaf(wA, bf2f(hA.w), acc3);
  }

  // combine even/odd halves (lane <-> lane^32, same channels, same head)
  acc0 += __shfl_xor(acc0, 32); acc1 += __shfl_xor(acc1, 32);
  acc2 += __shfl_xor(acc2, 32); acc3 += __shfl_xor(acc3, 32);
  denp += __shfl_xor(denp, 32);

  float inv = 1.f / (denp + 1e-16f);
  float o0 = elu_(acc0 * inv + b[c0]);
  float o1 = elu_(acc1 * inv + b[c0 + 1]);
  float o2 = elu_(acc2 * inv + b[c0 + 2]);
  float o3 = elu_(acc3 * inv + b[c0 + 3]);

  // stage y into wave-private LDS (half 0 only; both halves hold identical o)
  if (half == 0){
    *(float4*)(&yly[wid][c0]) = make_float4(o0, o1, o2, o3);
  }

  // alpha2 = y . (W2 @ a2): per-lane partial over 4 channels, reduce over hl
  float s2 = o0 * vs2[c0] + o1 * vs2[c0 + 1] + o2 * vs2[c0 + 2] + o3 * vs2[c0 + 3];
  float d2 = o0 * vd2[c0] + o1 * vd2[c0 + 1] + o2 * vd2[c0 + 2] + o3 * vd2[c0 + 3];
  #pragma unroll
  for (int m = 16; m; m >>= 1){ s2 += __shfl_xor(s2, m); d2 += __shfl_xor(d2, m); }
  if (lane == 0){ as2[node] = s2; ad2[node] = d2; }

  // drain the ds_write (wave-private data; no block barrier needed)
  asm volatile("s_waitcnt lgkmcnt(0)" ::: "memory");

  // z[node, lane] = sum_kk y[kk] * W2[kk, lane] via broadcast ds_read_b128
  float zacc = 0.f;
  const float* yw = yly[wid];
  #pragma unroll 4
  for (int q = 0; q < 32; ++q){
    float4 yv = *(const float4*)(yw + 4 * q);
    const float* wr = W2 + (q * 4) * 64 + lane;
    zacc = fmaf(yv.x, wr[0],   zacc);
    zacc = fmaf(yv.y, wr[64],  zacc);
    zacc = fmaf(yv.z, wr[128], zacc);
    zacc = fmaf(yv.w, wr[192], zacc);
  }
  z[((unsigned)node << 6) + lane] = f2bf(zacc);
}

// ------- layer-2 agg: half-wave, 4-edge unroll, packed ew (1 load/edge) -------
__global__ __launch_bounds__(256) void k_agg2(const int* __restrict__ off, const uint2* __restrict__ ew,
                                              const ushort* __restrict__ z,
                                              const float* __restrict__ b2, float* __restrict__ out){
  int node = blockIdx.x * 4 + (threadIdx.x >> 6);
  int lane = threadIdx.x & 63;
  int hl   = lane & 31;
  int half = lane >> 5;
  int c0   = hl * 2;
  int s0 = off[node], e0 = off[node + 1];

  float g0 = 0.f, g1 = 0.f, denp = 0.f;
  int k = s0 + half;
  for (; k + 6 < e0; k += 8){
    uint2 eA = ew[k],     eB = ew[k + 2];
    uint2 eC = ew[k + 4], eD = ew[k + 6];
    ushort2 zA = *(const ushort2*)(z + ((size_t)eA.x << 6) + c0);
    ushort2 zB = *(const ushort2*)(z + ((size_t)eB.x << 6) + c0);
    ushort2 zC = *(const ushort2*)(z + ((size_t)eC.x << 6) + c0);
    ushort2 zD = *(const ushort2*)(z + ((size_t)eD.x << 6) + c0);
    float wA = __uint_as_float(eA.y), wB = __uint_as_float(eB.y);
    float wC = __uint_as_float(eC.y), wD = __uint_as_float(eD.y);
    denp += (wA + wB) + (wC + wD);
    g0 = fmaf(wA, bf2f(zA.x), g0); g1 = fmaf(wA, bf2f(zA.y), g1);
    g0 = fmaf(wB, bf2f(zB.x), g0); g1 = fmaf(wB, bf2f(zB.y), g1);
    g0 = fmaf(wC, bf2f(zC.x), g0); g1 = fmaf(wC, bf2f(zC.y), g1);
    g0 = fmaf(wD, bf2f(zD.x), g0); g1 = fmaf(wD, bf2f(zD.y), g1);
  }
  for (; k < e0; k += 2){
    uint2 eA = ew[k];
    ushort2 zA = *(const ushort2*)(z + ((size_t)eA.x << 6) + c0);
    float wA = __uint_as_float(eA.y);
    denp += wA;
    g0 = fmaf(wA, bf2f(zA.x), g0); g1 = fmaf(wA, bf2f(zA.y), g1);
  }

  g0  += __shfl_xor(g0, 32);
  g1  += __shfl_xor(g1, 32);
  denp += __shfl_xor(denp, 32);

  if (half == 0){
    float inv = 1.f / (denp + 1e-16f);
    float2 o;
    o.x = elu_(g0 * inv + b2[c0]);
    o.y = elu_(g1 * inv + b2[c0 + 1]);
    *(float2*)(out + ((unsigned)node << 6) + c0) = o;
  }
}

// ---------------- host ----------------
extern "C" void kernel_launch(void* const* d_in, const int* in_sizes, int n_in,
                              void* d_out, int out_size, void* d_ws, size_t ws_size,
                              hipStream_t stream){
  const float* x      = (const float*)d_in[0];
  const int*   ei     = (const int*)d_in[1];
  const float* W1     = (const float*)d_in[2];
  const float* a_src1 = (const float*)d_in[3];
  const float* a_dst1 = (const float*)d_in[4];
  const float* b1     = (const float*)d_in[5];
  const float* W2     = (const float*)d_in[6];
  const float* a_src2 = (const float*)d_in[7];
  const float* a_dst2 = (const float*)d_in[8];
  const float* b2     = (const float*)d_in[9];
  float* out = (float*)d_out;

  // workspace (~57 MB); h1 (bf16) lives in d_out until k_agg2 overwrites it
  char* ws = (char*)d_ws;
  size_t o = 0;
  auto alloc = [&](size_t bytes){ size_t r = o; o = (o + bytes + 255) & ~(size_t)255; return r; };
  int*    tmpN = (int*)(ws + alloc((size_t)N_NODES * 4));
  int*    bs   = (int*)(ws + alloc(512));
  int*    off  = (int*)(ws + alloc((size_t)(N_NODES + 1) * 4));
  uint4*  csr4 = (uint4*)(ws + alloc((size_t)TOT_E * 16));
  uint2*  ew   = (uint2*)(ws + alloc((size_t)TOT_E * 8));
  float*  as1  = (float*)(ws + alloc((size_t)N_NODES * 2 * 4));
  float*  ad1  = (float*)(ws + alloc((size_t)N_NODES * 2 * 4));
  float*  as2  = (float*)(ws + alloc((size_t)N_NODES * 4));
  float*  ad2  = (float*)(ws + alloc((size_t)N_NODES * 4));
  float*  vs2  = (float*)(ws + alloc(512));
  float*  vd2  = (float*)(ws + alloc(512));
  ushort* z    = (ushort*)(ws + alloc((size_t)N_NODES * 64 * 2));
  ushort* h1   = (ushort*)d_out;
  (void)ws_size; (void)in_sizes; (void)n_in; (void)out_size;

  const int nblk_edges = (TOT_E + 255) / 256;
  const int nblk_scan  = (N_NODES + 1023) / 1024;
  const int nblk_wave4 = N_NODES / 4;

  // layer-1 GEMM (+ fused alpha1) first — k_fill_w needs as1/ad1
  k_gemm1<<<(N_NODES + 127) / 128, 256, 0, stream>>>(x, W1, a_src1, a_dst1, h1, as1, ad1, N_NODES);
  k_prep2<<<1, 128, 0, stream>>>(W2, a_src2, a_dst2, vs2, vd2);

  // CSR build with fused layer-1 edge-weight computation (packed records)
  hipMemsetAsync(tmpN, 0, (size_t)N_NODES * 4, stream);
  k_count <<<nblk_edges, 256, 0, stream>>>(ei, tmpN);
  k_scan1 <<<nblk_scan, 1024, 0, stream>>>(tmpN, off, bs);
  k_scan2 <<<1, 128, 0, stream>>>(bs, off, nblk_scan);
  k_scan3 <<<nblk_scan, 1024, 0, stream>>>(off, tmpN, bs);
  k_fill_w<<<nblk_edges, 256, 0, stream>>>(ei, tmpN, csr4, as1, ad1);

  // layer-1 agg: packed csr4, fused elu + z = y@W2 (LDS-broadcast) + alpha2
  k_agg1 <<<nblk_wave4, 256, 0, stream>>>(off, csr4, h1, b1, vs2, vd2, W2, z, as2, ad2);

  // layer-2 packed edge weights, then agg2
  k_ew2  <<<nblk_edges, 256, 0, stream>>>(csr4, as2, ad2, ew);
  k_agg2 <<<nblk_wave4, 256, 0, stream>>>(off, ew, z, b2, out);
}

// Round 11
// 409.222 us; speedup vs baseline: 1.6266x; 1.1399x over previous
//
#include <hip/hip_runtime.h>
#include <hip/hip_bf16.h>
#include <math.h>

#define N_NODES 100000
#define N_EDGES 1600000
#define TOT_E   (N_EDGES + N_NODES)

__device__ __forceinline__ float lrelu(float v){ return v > 0.f ? v : 0.2f * v; }
__device__ __forceinline__ float elu_(float v){ return v > 0.f ? v : expm1f(v); }
__device__ __forceinline__ ushort f2bf(float f){
  unsigned u = __float_as_uint(f);
  u = (u + 0x7FFFu + ((u >> 16) & 1u)) >> 16;   // RNE
  return (ushort)u;
}
__device__ __forceinline__ float bf2f(ushort u){
  return __uint_as_float(((unsigned)u) << 16);
}
__device__ __forceinline__ float bflo(unsigned p){ return __uint_as_float(p << 16); }
__device__ __forceinline__ float bfhi(unsigned p){ return __uint_as_float(p & 0xffff0000u); }

// ---------------- CSR build (by dst) ----------------
__global__ __launch_bounds__(256) void k_count(const int* __restrict__ ei, int* __restrict__ cnt){
  int i = blockIdx.x * 256 + threadIdx.x;
  if (i >= TOT_E) return;
  int d = (i < N_EDGES) ? ei[N_EDGES + i] : (i - N_EDGES);
  atomicAdd(&cnt[d], 1);
}

__global__ __launch_bounds__(1024) void k_scan1(const int* __restrict__ cnt, int* __restrict__ off,
                                                int* __restrict__ bs){
  __shared__ int s[1024];
  int t = threadIdx.x;
  int i = blockIdx.x * 1024 + t;
  int v = (i < N_NODES) ? cnt[i] : 0;
  s[t] = v;
  __syncthreads();
  for (int o = 1; o < 1024; o <<= 1){
    int tmp = 0;
    if (t >= o) tmp = s[t - o];
    __syncthreads();
    if (t >= o) s[t] += tmp;
    __syncthreads();
  }
  if (i < N_NODES) off[i] = s[t] - v;
  if (t == 1023) bs[blockIdx.x] = s[1023];
}

// parallel scan of the 98 block sums
__global__ __launch_bounds__(128) void k_scan2(int* __restrict__ bs, int* __restrict__ off, int nb){
  __shared__ int s[128];
  int t = threadIdx.x;
  int v = (t < nb) ? bs[t] : 0;
  s[t] = v;
  __syncthreads();
  #pragma unroll
  for (int o = 1; o < 128; o <<= 1){
    int tmp = 0;
    if (t >= o) tmp = s[t - o];
    __syncthreads();
    if (t >= o) s[t] += tmp;
    __syncthreads();
  }
  if (t < nb) bs[t] = s[t] - v;            // exclusive prefix
  if (t == nb - 1) off[N_NODES] = s[t];    // grand total
}

__global__ __launch_bounds__(1024) void k_scan3(int* __restrict__ off, int* __restrict__ cur,
                                                const int* __restrict__ bs){
  int i = blockIdx.x * 1024 + threadIdx.x;
  if (i < N_NODES){
    int v = off[i] + bs[blockIdx.x];
    off[i] = v;
    cur[i] = v;
  }
}

// fill packed CSR {src, w_head0, w_head1, dst} (runs AFTER gemm1)
__global__ __launch_bounds__(256) void k_fill_w(const int* __restrict__ ei, int* __restrict__ cur,
                                                uint4* __restrict__ csr4,
                                                const float* __restrict__ as1, const float* __restrict__ ad1){
  int i = blockIdx.x * 256 + threadIdx.x;
  if (i >= TOT_E) return;
  int s, d;
  if (i < N_EDGES){ s = ei[i]; d = ei[N_EDGES + i]; }
  else            { s = d = i - N_EDGES; }
  int p = atomicAdd(&cur[d], 1);
  float2 a  = *(const float2*)(as1 + 2u * (unsigned)s);
  float2 ad = *(const float2*)(ad1 + 2u * (unsigned)d);
  uint4 v;
  v.x = (unsigned)s;
  v.y = __float_as_uint(__expf(lrelu(a.x + ad.x)));
  v.z = __float_as_uint(__expf(lrelu(a.y + ad.y)));
  v.w = (unsigned)d;
  csr4[p] = v;
}

// layer-2 packed edge records {src, w2} (runs AFTER agg1)
__global__ __launch_bounds__(256) void k_ew2(const uint4* __restrict__ csr4,
                                             const float* __restrict__ as2, const float* __restrict__ ad2,
                                             uint2* __restrict__ ew){
  int i = blockIdx.x * 256 + threadIdx.x;
  if (i >= TOT_E) return;
  uint4 v = csr4[i];
  float w = __expf(lrelu(as2[v.x] + ad2[v.w]));
  ew[i] = make_uint2(v.x, __float_as_uint(w));
}

// ------- layer-1 GEMM (LDS-staged) fused with alpha1; h stored bf16 (in d_out) -------
__global__ __launch_bounds__(256) void k_gemm1(const float* __restrict__ x, const float* __restrict__ W,
                                               const float* __restrict__ a_src, const float* __restrict__ a_dst,
                                               ushort* __restrict__ h, float* __restrict__ as1,
                                               float* __restrict__ ad1, int n){
  __shared__ float sx[128][36];
  __shared__ float sw[32][132];
  const int tid  = threadIdx.x;
  const int cg   = tid & 7;
  const int slot = tid >> 3;
  const int rbase = blockIdx.x * 128;
  const int r0   = rbase + slot * 4;
  const int col0 = cg * 16;

  float acc[4][16] = {};

  for (int kc = 0; kc < 4; ++kc){
    __syncthreads();
    #pragma unroll
    for (int i = 0; i < 4; ++i){
      int f   = tid + 256 * i;
      int row = f >> 3;
      int c4  = f & 7;
      int gr  = rbase + row; if (gr > n - 1) gr = n - 1;
      float4 v = *(const float4*)(x + (size_t)gr * 128 + kc * 32 + c4 * 4);
      *(float4*)(&sx[row][c4 * 4]) = v;
    }
    #pragma unroll
    for (int i = 0; i < 4; ++i){
      int f  = tid + 256 * i;
      int k  = f >> 5;
      int c4 = f & 31;
      float4 v = *(const float4*)(W + (size_t)(kc * 32 + k) * 128 + c4 * 4);
      *(float4*)(&sw[k][c4 * 4]) = v;
    }
    __syncthreads();

    #pragma unroll 8
    for (int j = 0; j < 32; ++j){
      float4 w0 = *(const float4*)(&sw[j][col0]);
      float4 w1 = *(const float4*)(&sw[j][col0 + 4]);
      float4 w2 = *(const float4*)(&sw[j][col0 + 8]);
      float4 w3 = *(const float4*)(&sw[j][col0 + 12]);
      #pragma unroll
      for (int i = 0; i < 4; ++i){
        float xv = sx[slot * 4 + i][j];
        acc[i][0]  = fmaf(xv, w0.x, acc[i][0]);  acc[i][1]  = fmaf(xv, w0.y, acc[i][1]);
        acc[i][2]  = fmaf(xv, w0.z, acc[i][2]);  acc[i][3]  = fmaf(xv, w0.w, acc[i][3]);
        acc[i][4]  = fmaf(xv, w1.x, acc[i][4]);  acc[i][5]  = fmaf(xv, w1.y, acc[i][5]);
        acc[i][6]  = fmaf(xv, w1.z, acc[i][6]);  acc[i][7]  = fmaf(xv, w1.w, acc[i][7]);
        acc[i][8]  = fmaf(xv, w2.x, acc[i][8]);  acc[i][9]  = fmaf(xv, w2.y, acc[i][9]);
        acc[i][10] = fmaf(xv, w2.z, acc[i][10]); acc[i][11] = fmaf(xv, w2.w, acc[i][11]);
        acc[i][12] = fmaf(xv, w3.x, acc[i][12]); acc[i][13] = fmaf(xv, w3.y, acc[i][13]);
        acc[i][14] = fmaf(xv, w3.z, acc[i][14]); acc[i][15] = fmaf(xv, w3.w, acc[i][15]);
      }
    }
  }

  #pragma unroll
  for (int i = 0; i < 4; ++i){
    int r = r0 + i;
    float sp = 0.f, dp = 0.f;
    #pragma unroll
    for (int j = 0; j < 16; ++j){
      sp = fmaf(acc[i][j], a_src[col0 + j], sp);
      dp = fmaf(acc[i][j], a_dst[col0 + j], dp);
    }
    float s0 = (col0 < 64) ? sp : 0.f, s1 = (col0 < 64) ? 0.f : sp;
    float d0 = (col0 < 64) ? dp : 0.f, d1 = (col0 < 64) ? 0.f : dp;
    #pragma unroll
    for (int m = 1; m <= 4; m <<= 1){
      s0 += __shfl_xor(s0, m); s1 += __shfl_xor(s1, m);
      d0 += __shfl_xor(d0, m); d1 += __shfl_xor(d1, m);
    }
    if (r < n){
      union { uint4 q[2]; ushort us[16]; } pk;
      #pragma unroll
      for (int j = 0; j < 16; ++j) pk.us[j] = f2bf(acc[i][j]);
      uint4* dst = (uint4*)(h + (size_t)r * 128 + col0);
      dst[0] = pk.q[0]; dst[1] = pk.q[1];
      if (cg == 0){
        as1[2 * r] = s0; as1[2 * r + 1] = s1;
        ad1[2 * r] = d0; ad1[2 * r + 1] = d1;
      }
    }
  }
}

// ------- layer-2 attention vectors: vs[k] = sum_c W2[k,c]*a2[c] -------
__global__ void k_prep2(const float* __restrict__ W2, const float* __restrict__ a_src2,
                        const float* __restrict__ a_dst2, float* __restrict__ vs, float* __restrict__ vd){
  int k = threadIdx.x;  // 128 threads
  float s = 0.f, d = 0.f;
  for (int c = 0; c < 64; ++c){
    float w = W2[k * 64 + c];
    s = fmaf(w, a_src2[c], s);
    d = fmaf(w, a_dst2[c], d);
  }
  vs[k] = s; vd[k] = d;
}

// ------- layer-1 agg: FULL-WAVE, 1 row/instr, scalar edge records -------
// Whole wave per edge; lane covers channels 2*lane,2*lane+1 (one uint = 2 bf16,
// 64 lanes x 4B = one 256B h row per instruction). csr4[k] is wave-uniform ->
// forced to s_load via readfirstlane; h address = SGPR base + lane offset.
// No acc/den cross-lane reduces. Unroll 8 = 8 rows in flight.
__global__ __launch_bounds__(256) void k_agg1(const int* __restrict__ off, const uint4* __restrict__ csr4,
                                              const ushort* __restrict__ h,
                                              const float* __restrict__ b,
                                              const float* __restrict__ vs2, const float* __restrict__ vd2,
                                              const float* __restrict__ W2,
                                              ushort* __restrict__ z, float* __restrict__ as2,
                                              float* __restrict__ ad2){
  __shared__ float yly[4][128];          // per-wave y row (wave-private)
  int wid  = threadIdx.x >> 6;
  int node = blockIdx.x * 4 + wid;
  int lane = threadIdx.x & 63;
  int head = lane >> 5;                  // lanes 0-31: head0 ch 0..63; 32-63: head1 ch 64..127
  int c0   = lane * 2;
  int s0 = off[node], e0 = off[node + 1];

  float acc0 = 0.f, acc1 = 0.f, den = 0.f;
  int k = s0;
  for (; k + 7 < e0; k += 8){
    int ku = __builtin_amdgcn_readfirstlane(k);
    uint4 eA = csr4[ku],     eB = csr4[ku + 1], eC = csr4[ku + 2], eD = csr4[ku + 3];
    uint4 eE = csr4[ku + 4], eF = csr4[ku + 5], eG = csr4[ku + 6], eH = csr4[ku + 7];
    unsigned hA = *(const unsigned*)(h + ((size_t)eA.x << 7) + c0);
    unsigned hB = *(const unsigned*)(h + ((size_t)eB.x << 7) + c0);
    unsigned hC = *(const unsigned*)(h + ((size_t)eC.x << 7) + c0);
    unsigned hD = *(const unsigned*)(h + ((size_t)eD.x << 7) + c0);
    unsigned hE = *(const unsigned*)(h + ((size_t)eE.x << 7) + c0);
    unsigned hF = *(const unsigned*)(h + ((size_t)eF.x << 7) + c0);
    unsigned hG = *(const unsigned*)(h + ((size_t)eG.x << 7) + c0);
    unsigned hH = *(const unsigned*)(h + ((size_t)eH.x << 7) + c0);
    float wA = __uint_as_float(head ? eA.z : eA.y);
    float wB = __uint_as_float(head ? eB.z : eB.y);
    float wC = __uint_as_float(head ? eC.z : eC.y);
    float wD = __uint_as_float(head ? eD.z : eD.y);
    float wE = __uint_as_float(head ? eE.z : eE.y);
    float wF = __uint_as_float(head ? eF.z : eF.y);
    float wG = __uint_as_float(head ? eG.z : eG.y);
    float wH = __uint_as_float(head ? eH.z : eH.y);
    den += ((wA + wB) + (wC + wD)) + ((wE + wF) + (wG + wH));
    acc0 = fmaf(wA, bflo(hA), acc0); acc1 = fmaf(wA, bfhi(hA), acc1);
    acc0 = fmaf(wB, bflo(hB), acc0); acc1 = fmaf(wB, bfhi(hB), acc1);
    acc0 = fmaf(wC, bflo(hC), acc0); acc1 = fmaf(wC, bfhi(hC), acc1);
    acc0 = fmaf(wD, bflo(hD), acc0); acc1 = fmaf(wD, bfhi(hD), acc1);
    acc0 = fmaf(wE, bflo(hE), acc0); acc1 = fmaf(wE, bfhi(hE), acc1);
    acc0 = fmaf(wF, bflo(hF), acc0); acc1 = fmaf(wF, bfhi(hF), acc1);
    acc0 = fmaf(wG, bflo(hG), acc0); acc1 = fmaf(wG, bfhi(hG), acc1);
    acc0 = fmaf(wH, bflo(hH), acc0); acc1 = fmaf(wH, bfhi(hH), acc1);
  }
  for (; k < e0; ++k){
    int ku = __builtin_amdgcn_readfirstlane(k);
    uint4 eA = csr4[ku];
    unsigned hA = *(const unsigned*)(h + ((size_t)eA.x << 7) + c0);
    float wA = __uint_as_float(head ? eA.z : eA.y);
    den += wA;
    acc0 = fmaf(wA, bflo(hA), acc0); acc1 = fmaf(wA, bfhi(hA), acc1);
  }

  // den is replicated across lanes of the same head; no reduce needed
  float inv = 1.f / (den + 1e-16f);
  float o0 = elu_(acc0 * inv + b[c0]);
  float o1 = elu_(acc1 * inv + b[c0 + 1]);

  // stage y (each lane owns 2 unique channels)
  *(float2*)(&yly[wid][c0]) = make_float2(o0, o1);

  // alpha2 = y . (W2 @ a2): 2-channel partial, reduce over all 64 lanes
  float s2 = fmaf(o0, vs2[c0], o1 * vs2[c0 + 1]);
  float d2 = fmaf(o0, vd2[c0], o1 * vd2[c0 + 1]);
  #pragma unroll
  for (int m = 32; m; m >>= 1){ s2 += __shfl_xor(s2, m); d2 += __shfl_xor(d2, m); }
  if (lane == 0){ as2[node] = s2; ad2[node] = d2; }

  // drain ds_write before same-wave broadcast reads
  asm volatile("s_waitcnt lgkmcnt(0)" ::: "memory");

  // z[node, lane] = sum_kk y[kk] * W2[kk, lane] via broadcast ds_read_b128
  float zacc = 0.f;
  const float* yw = yly[wid];
  #pragma unroll 4
  for (int q = 0; q < 32; ++q){
    float4 yv = *(const float4*)(yw + 4 * q);
    const float* wr = W2 + (q * 4) * 64 + lane;
    zacc = fmaf(yv.x, wr[0],   zacc);
    zacc = fmaf(yv.y, wr[64],  zacc);
    zacc = fmaf(yv.z, wr[128], zacc);
    zacc = fmaf(yv.w, wr[192], zacc);
  }
  z[((unsigned)node << 6) + lane] = f2bf(zacc);
}

// ------- layer-2 agg: FULL-WAVE, 1 row/instr, scalar edge records -------
// lane = channel (64 ch); z row = 64 lanes x 2B = 128B per instruction.
// Zero cross-lane reduces.
__global__ __launch_bounds__(256) void k_agg2(const int* __restrict__ off, const uint2* __restrict__ ew,
                                              const ushort* __restrict__ z,
                                              const float* __restrict__ b2, float* __restrict__ out){
  int node = blockIdx.x * 4 + (threadIdx.x >> 6);
  int lane = threadIdx.x & 63;
  int s0 = off[node], e0 = off[node + 1];

  float acc = 0.f, den = 0.f;
  int k = s0;
  for (; k + 7 < e0; k += 8){
    int ku = __builtin_amdgcn_readfirstlane(k);
    uint2 eA = ew[ku],     eB = ew[ku + 1], eC = ew[ku + 2], eD = ew[ku + 3];
    uint2 eE = ew[ku + 4], eF = ew[ku + 5], eG = ew[ku + 6], eH = ew[ku + 7];
    ushort zA = z[((size_t)eA.x << 6) + lane];
    ushort zB = z[((size_t)eB.x << 6) + lane];
    ushort zC = z[((size_t)eC.x << 6) + lane];
    ushort zD = z[((size_t)eD.x << 6) + lane];
    ushort zE = z[((size_t)eE.x << 6) + lane];
    ushort zF = z[((size_t)eF.x << 6) + lane];
    ushort zG = z[((size_t)eG.x << 6) + lane];
    ushort zH = z[((size_t)eH.x << 6) + lane];
    float wA = __uint_as_float(eA.y), wB = __uint_as_float(eB.y);
    float wC = __uint_as_float(eC.y), wD = __uint_as_float(eD.y);
    float wE = __uint_as_float(eE.y), wF = __uint_as_float(eF.y);
    float wG = __uint_as_float(eG.y), wH = __uint_as_float(eH.y);
    den += ((wA + wB) + (wC + wD)) + ((wE + wF) + (wG + wH));
    acc = fmaf(wA, bf2f(zA), acc); acc = fmaf(wB, bf2f(zB), acc);
    acc = fmaf(wC, bf2f(zC), acc); acc = fmaf(wD, bf2f(zD), acc);
    acc = fmaf(wE, bf2f(zE), acc); acc = fmaf(wF, bf2f(zF), acc);
    acc = fmaf(wG, bf2f(zG), acc); acc = fmaf(wH, bf2f(zH), acc);
  }
  for (; k < e0; ++k){
    int ku = __builtin_amdgcn_readfirstlane(k);
    uint2 eA = ew[ku];
    ushort zA = z[((size_t)eA.x << 6) + lane];
    float wA = __uint_as_float(eA.y);
    den += wA;
    acc = fmaf(wA, bf2f(zA), acc);
  }

  float inv = 1.f / (den + 1e-16f);
  out[((unsigned)node << 6) + lane] = elu_(acc * inv + b2[lane]);
}

// ---------------- host ----------------
extern "C" void kernel_launch(void* const* d_in, const int* in_sizes, int n_in,
                              void* d_out, int out_size, void* d_ws, size_t ws_size,
                              hipStream_t stream){
  const float* x      = (const float*)d_in[0];
  const int*   ei     = (const int*)d_in[1];
  const float* W1     = (const float*)d_in[2];
  const float* a_src1 = (const float*)d_in[3];
  const float* a_dst1 = (const float*)d_in[4];
  const float* b1     = (const float*)d_in[5];
  const float* W2     = (const float*)d_in[6];
  const float* a_src2 = (const float*)d_in[7];
  const float* a_dst2 = (const float*)d_in[8];
  const float* b2     = (const float*)d_in[9];
  float* out = (float*)d_out;

  // workspace (~57 MB); h1 (bf16) lives in d_out until k_agg2 overwrites it
  char* ws = (char*)d_ws;
  size_t o = 0;
  auto alloc = [&](size_t bytes){ size_t r = o; o = (o + bytes + 255) & ~(size_t)255; return r; };
  int*    tmpN = (int*)(ws + alloc((size_t)N_NODES * 4));
  int*    bs   = (int*)(ws + alloc(512));
  int*    off  = (int*)(ws + alloc((size_t)(N_NODES + 1) * 4));
  uint4*  csr4 = (uint4*)(ws + alloc((size_t)TOT_E * 16));
  uint2*  ew   = (uint2*)(ws + alloc((size_t)TOT_E * 8));
  float*  as1  = (float*)(ws + alloc((size_t)N_NODES * 2 * 4));
  float*  ad1  = (float*)(ws + alloc((size_t)N_NODES * 2 * 4));
  float*  as2  = (float*)(ws + alloc((size_t)N_NODES * 4));
  float*  ad2  = (float*)(ws + alloc((size_t)N_NODES * 4));
  float*  vs2  = (float*)(ws + alloc(512));
  float*  vd2  = (float*)(ws + alloc(512));
  ushort* z    = (ushort*)(ws + alloc((size_t)N_NODES * 64 * 2));
  ushort* h1   = (ushort*)d_out;
  (void)ws_size; (void)in_sizes; (void)n_in; (void)out_size;

  const int nblk_edges = (TOT_E + 255) / 256;
  const int nblk_scan  = (N_NODES + 1023) / 1024;
  const int nblk_wave4 = N_NODES / 4;

  // layer-1 GEMM (+ fused alpha1) first — k_fill_w needs as1/ad1
  k_gemm1<<<(N_NODES + 127) / 128, 256, 0, stream>>>(x, W1, a_src1, a_dst1, h1, as1, ad1, N_NODES);
  k_prep2<<<1, 128, 0, stream>>>(W2, a_src2, a_dst2, vs2, vd2);

  // CSR build with fused layer-1 edge-weight computation (packed records)
  hipMemsetAsync(tmpN, 0, (size_t)N_NODES * 4, stream);
  k_count <<<nblk_edges, 256, 0, stream>>>(ei, tmpN);
  k_scan1 <<<nblk_scan, 1024, 0, stream>>>(tmpN, off, bs);
  k_scan2 <<<1, 128, 0, stream>>>(bs, off, nblk_scan);
  k_scan3 <<<nblk_scan, 1024, 0, stream>>>(off, tmpN, bs);
  k_fill_w<<<nblk_edges, 256, 0, stream>>>(ei, tmpN, csr4, as1, ad1);

  // layer-1 agg: full-wave rows, scalar edge records, fused z=y@W2 + alpha2
  k_agg1 <<<nblk_wave4, 256, 0, stream>>>(off, csr4, h1, b1, vs2, vd2, W2, z, as2, ad2);

  // layer-2 packed edge weights, then full-wave agg2
  k_ew2  <<<nblk_edges, 256, 0, stream>>>(csr4, as2, ad2, ew);
  k_agg2 <<<nblk_wave4, 256, 0, stream>>>(off, ew, z, b2, out);
}